// Round 1
// baseline (283.996 us; speedup 1.0000x reference)
//
#include <hip/hip_runtime.h>
#include <cstdint>
#include <cstddef>

typedef unsigned short u16;
typedef __attribute__((ext_vector_type(4))) float f32x4;
typedef __attribute__((ext_vector_type(8))) short bf16x8;

#define SEQT 2048
#define DIMN 2048

__device__ __forceinline__ float bf2f(u16 h){
  union { unsigned int u; float f; } v; v.u = ((unsigned int)h) << 16; return v.f;
}
__device__ __forceinline__ u16 f2bf(float f){
  union { float f; unsigned int u; } v; v.f = f;
  unsigned int r = v.u + 0x7fffu + ((v.u >> 16) & 1u);
  return (u16)(r >> 16);
}

typedef const __attribute__((address_space(1))) unsigned int* gas1_t;
typedef __attribute__((address_space(3))) unsigned int* las3_t;
__device__ __forceinline__ void gload_lds16(const void* g, void* l){
  __builtin_amdgcn_global_load_lds((gas1_t)g, (las3_t)l, 16, 0, 0);
}

// ---------------------------------------------------------------------------
// Generic NT GEMM: C[m,n] = sum_k A[m,k]*B[n,k], A:(M,K) bf16, B:(N,K) bf16.
// BM=128, BN=128 fixed; 256 threads = 4 waves in 2x2, each 64x64 (4x4 frags).
// Split-K via gridDim.z (EPI=0 only): block z writes partial to C + z*M*N.
// EPI: 0 = f32 store, 1 = bf16 store, 2 = relu^2 -> bf16, 3 = f32 add-into.
// ---------------------------------------------------------------------------
template<int BK, int EPI>
__global__ __launch_bounds__(256, 2) void gemm_nt(
    const u16* __restrict__ A, const u16* __restrict__ B, void* __restrict__ Cv,
    int M, int N, int K)
{
  __shared__ u16 As[128 * BK];
  __shared__ u16 Bs[128 * BK];
  constexpr int ITER = (128 * BK) / 2048;
  constexpr int GM = BK / 8 - 1;
  const int t = threadIdx.x;
  const int w = t >> 6, l = t & 63;
  const int lr = l & 15, lg = l >> 4;
  const int brow = blockIdx.x << 7, bcol = blockIdx.y << 7;
  const int wr = (w >> 1) << 6, wc = (w & 1) << 6;
  const int Kc = K / gridDim.z;
  const int kbeg = blockIdx.z * Kc;
  const int kend = kbeg + Kc;
  f32x4 acc[4][4] = {};
  for (int k0 = kbeg; k0 < kend; k0 += BK) {
    __syncthreads();
#pragma unroll
    for (int i = 0; i < ITER; ++i) {
      int eo = i * 2048 + t * 8;
      int row = eo / BK;
      int cg = (eo & (BK - 1)) >> 3;
      int scol = ((cg ^ row) & GM) << 3;       // pre-swizzled global source
      gload_lds16(A + (size_t)(brow + row) * K + k0 + scol, &As[eo]);
      gload_lds16(B + (size_t)(bcol + row) * K + k0 + scol, &Bs[eo]);
    }
    __syncthreads();
#pragma unroll
    for (int ks = 0; ks < BK / 32; ++ks) {
      bf16x8 aF[4], bF[4];
#pragma unroll
      for (int m = 0; m < 4; ++m) {
        int row = wr + m * 16 + lr;
        int kg = ks * 4 + lg;
        aF[m] = *(const bf16x8*)&As[row * BK + (((kg ^ row) & GM) << 3)];
      }
#pragma unroll
      for (int n = 0; n < 4; ++n) {
        int row = wc + n * 16 + lr;
        int kg = ks * 4 + lg;
        bF[n] = *(const bf16x8*)&Bs[row * BK + (((kg ^ row) & GM) << 3)];
      }
#pragma unroll
      for (int m = 0; m < 4; ++m)
#pragma unroll
        for (int n = 0; n < 4; ++n)
          acc[m][n] = __builtin_amdgcn_mfma_f32_16x16x32_bf16(aF[m], bF[n], acc[m][n], 0, 0, 0);
    }
  }
  const size_t zoff = (size_t)blockIdx.z * (size_t)M * (size_t)N;
#pragma unroll
  for (int m = 0; m < 4; ++m)
#pragma unroll
    for (int n = 0; n < 4; ++n)
#pragma unroll
      for (int j = 0; j < 4; ++j) {
        int row = brow + wr + m * 16 + lg * 4 + j;
        int col = bcol + wc + n * 16 + lr;
        float v = acc[m][n][j];
        if constexpr (EPI == 0) ((float*)Cv)[zoff + (size_t)row * N + col] = v;
        else if constexpr (EPI == 1) ((u16*)Cv)[(size_t)row * N + col] = f2bf(v);
        else if constexpr (EPI == 2) { float r = v > 0.f ? v * v : 0.f; ((u16*)Cv)[(size_t)row * N + col] = f2bf(r); }
        else ((float*)Cv)[(size_t)row * N + col] += v;
      }
}

// Sum split-K partials -> bf16
__global__ __launch_bounds__(256) void redcvt_k(const float* __restrict__ parts,
                                                u16* __restrict__ out, int n, int S)
{
  int i = blockIdx.x * 256 + threadIdx.x;
  if (i >= n) return;
  float s = 0.f;
  for (int z = 0; z < S; ++z) s += parts[(size_t)z * n + i];
  out[i] = f2bf(s);
}

// ---------------------------------------------------------------------------
// Weight f32 -> bf16 conversion (all weights packed into one dest region)
// ---------------------------------------------------------------------------
struct ConvArgs { const float* s[15]; int off[16]; };
__global__ __launch_bounds__(256) void conv_weights(ConvArgs a, u16* __restrict__ dst, int total)
{
  int i = blockIdx.x * 256 + threadIdx.x;
  if (i >= total) return;
  int seg = 0;
#pragma unroll
  for (int k = 1; k < 15; ++k) if (i >= a.off[k]) seg = k;
  dst[i] = f2bf(a.s[seg][i - a.off[seg]]);
}

// rmsnorm over DIM=2048, f32 in -> bf16 out (with weight)
__global__ __launch_bounds__(256) void rmsnorm_k(const float* __restrict__ x,
                                                 const float* __restrict__ wg,
                                                 u16* __restrict__ o, float eps)
{
  int row = blockIdx.x;
  const float* xr = x + (size_t)row * DIMN;
  float v[8]; float ss = 0.f;
#pragma unroll
  for (int i = 0; i < 8; ++i) { v[i] = xr[threadIdx.x + i * 256]; ss += v[i] * v[i]; }
#pragma unroll
  for (int m = 1; m < 64; m <<= 1) ss += __shfl_xor(ss, m);
  __shared__ float red[4];
  if ((threadIdx.x & 63) == 0) red[threadIdx.x >> 6] = ss;
  __syncthreads();
  float tot = red[0] + red[1] + red[2] + red[3];
  float rs = rsqrtf(tot * (1.0f / DIMN) + eps);
  u16* orow = o + (size_t)row * DIMN;
#pragma unroll
  for (int i = 0; i < 8; ++i) { int c = threadIdx.x + i * 256; orow[c] = f2bf(v[i] * rs * wg[c]); }
}

// per-head rms (HEPS), optional RoPE (first 64 dims), optional gain; in-place bf16
__global__ __launch_bounds__(256) void qkproc_k(u16* __restrict__ qk, int rowstride,
                                                const float* __restrict__ gain, int do_rope)
{
  int tpos = blockIdx.x;
  int hh = blockIdx.y * 4 + (threadIdx.x >> 6);
  int l = threadIdx.x & 63;
  u16* p = qk + (size_t)tpos * rowstride + hh * 128;
  float v0 = bf2f(p[l]), v1 = bf2f(p[l + 64]);
  float ss = v0 * v0 + v1 * v1;
#pragma unroll
  for (int m = 1; m < 64; m <<= 1) ss += __shfl_xor(ss, m);
  float rs = rsqrtf(ss * (1.0f / 128.0f) + 1.1920929e-07f);
  v0 *= rs; v1 *= rs;
  if (do_rope) {
    int i = l & 31;
    float fr = __expf(-(float)i * 0.28782313662425574f); // ln(10000)/32
    float f = (float)tpos * fr;
    float c = cosf(f), sn = sinf(f);
    float o = __shfl_xor(v0, 32);
    v0 = (l < 32) ? (v0 * c + o * sn) : (v0 * c - o * sn);
  }
  if (gain) { float g = gain[hh]; v0 *= g; v1 *= g; }
  p[l] = f2bf(v0); p[l + 64] = f2bf(v1);
}

// t16[2048][32] = value_emb[ids] @ vpB.T   (f32 inputs, bf16 out)
__global__ __launch_bounds__(256) void g9_k(const int* __restrict__ ids,
                                            const float* __restrict__ emb,
                                            const float* __restrict__ vpB,
                                            u16* __restrict__ t16)
{
  int idx = blockIdx.x * 256 + threadIdx.x;   // 2048*32
  int m = idx >> 5, n = idx & 31;
  int id = ids[m]; id = id < 0 ? 0 : (id > 50256 ? 50256 : id);
  const float* e = emb + (size_t)id * 64;
  const float* wr = vpB + n * 64;
  float s = 0.f;
#pragma unroll
  for (int k = 0; k < 64; ++k) s += e[k] * wr[k];
  t16[idx] = f2bf(s);
}

// vt[kh][d][t] = bf16(v32[t][kh*128+d])
__global__ __launch_bounds__(256) void vtprep_k(const float* __restrict__ v32, u16* __restrict__ vt)
{
  int o = blockIdx.x * 256 + threadIdx.x;     // 2048*512
  int kh = o >> 18, d = (o >> 11) & 127, tp = o & 2047;
  vt[o] = f2bf(v32[(size_t)tp * 512 + kh * 128 + d]);
}

// out = x + scale[col] * g   (f32, vectorized float4)
__global__ __launch_bounds__(256) void resid_k(const float* __restrict__ xin,
                                               const float* __restrict__ gin,
                                               const float* __restrict__ sc,
                                               float* __restrict__ out)
{
  int i = blockIdx.x * 256 + threadIdx.x;     // float4 index
  float4 xv = ((const float4*)xin)[i];
  float4 gv = ((const float4*)gin)[i];
  float4 sv = ((const float4*)sc)[i & (DIMN / 4 - 1)];
  float4 ov;
  ov.x = xv.x + sv.x * gv.x; ov.y = xv.y + sv.y * gv.y;
  ov.z = xv.z + sv.z * gv.z; ov.w = xv.w + sv.w * gv.w;
  ((float4*)out)[i] = ov;
}

// ---------------------------------------------------------------------------
// Flash attention, sliding window. 1 block = 64 q-rows x 1 head; 4 waves,
// wave owns 16 q-rows. K staged swizzled in LDS; V pre-transposed in global.
// ---------------------------------------------------------------------------
__global__ __launch_bounds__(256, 2) void attn_kernel(
    const u16* __restrict__ Q, const u16* __restrict__ Kx, const u16* __restrict__ Vt,
    u16* __restrict__ O, const int* __restrict__ wptr)
{
  __shared__ u16 Ks[64 * 128];
  __shared__ u16 Vs[128 * 64];
  __shared__ u16 Pl[4][16 * 64];
  const int t = threadIdx.x;
  const int w = t >> 6, l = t & 63;
  const int lr = l & 15, lg = l >> 4;
  const int h = blockIdx.y, kh = h >> 2;
  const int qb0 = blockIdx.x << 6;
  int W = *wptr;
  if (W > 65536 || W < 0) { union { int i; float f; } u; u.i = W; W = (int)u.f; }
  if (W < 1) W = 1;
  if (W > SEQT) W = SEQT;
  bf16x8 qF[4];
  {
    const u16* qb = Q + (size_t)(qb0 + w * 16 + lr) * DIMN + h * 128;
#pragma unroll
    for (int ks = 0; ks < 4; ++ks) qF[ks] = *(const bf16x8*)(qb + ks * 32 + lg * 8);
  }
  f32x4 oacc[8] = {};
  float mrow[4] = {-1e30f, -1e30f, -1e30f, -1e30f};
  float lsum[4] = {0.f, 0.f, 0.f, 0.f};
  int kstart = qb0 - W + 1;
  if (kstart < 0) kstart = 0;
  kstart &= ~63;
  const float scl = 0.08838834764831845f;   // 128^-0.5
  for (int kc = kstart; kc <= qb0; kc += 64) {
    __syncthreads();
#pragma unroll
    for (int i = 0; i < 4; ++i) {
      int eo = i * 2048 + t * 8;
      {
        int row = eo >> 7, cg = (eo >> 3) & 15;
        gload_lds16(Kx + (size_t)(kc + row) * 512 + kh * 128 + (((cg ^ row) & 15) << 3), &Ks[eo]);
      }
      {
        int d = eo >> 6, kg = (eo >> 3) & 7;
        gload_lds16(Vt + (size_t)kh * (128 * SEQT) + (size_t)d * SEQT + kc + (((kg ^ d) & 7) << 3), &Vs[eo]);
      }
    }
    __syncthreads();
    f32x4 sf[4] = {};
#pragma unroll
    for (int ks = 0; ks < 4; ++ks) {
#pragma unroll
      for (int n = 0; n < 4; ++n) {
        int row = n * 16 + lr;
        int kg = ks * 4 + lg;
        bf16x8 kF = *(const bf16x8*)&Ks[(row << 7) + (((kg ^ row) & 15) << 3)];
        sf[n] = __builtin_amdgcn_mfma_f32_16x16x32_bf16(qF[ks], kF, sf[n], 0, 0, 0);
      }
    }
    float p[4][4];
#pragma unroll
    for (int j = 0; j < 4; ++j) {
      int qi = qb0 + w * 16 + lg * 4 + j;
      float pm = -1e30f;
#pragma unroll
      for (int n = 0; n < 4; ++n) {
        int kj = kc + n * 16 + lr;
        float sv = (kj <= qi && (qi - kj) < W) ? sf[n][j] * scl : -1e30f;
        p[n][j] = sv;
        pm = fmaxf(pm, sv);
      }
#pragma unroll
      for (int mm = 1; mm < 16; mm <<= 1) pm = fmaxf(pm, __shfl_xor(pm, mm));
      float mn = fmaxf(mrow[j], pm);
      float resc = __expf(mrow[j] - mn);
      float ls = 0.f;
#pragma unroll
      for (int n = 0; n < 4; ++n) {
        float pv = (p[n][j] > -1e29f) ? __expf(p[n][j] - mn) : 0.f;
        p[n][j] = pv;
        ls += pv;
      }
#pragma unroll
      for (int mm = 1; mm < 16; mm <<= 1) ls += __shfl_xor(ls, mm);
      lsum[j] = lsum[j] * resc + ls;
      mrow[j] = mn;
#pragma unroll
      for (int nd = 0; nd < 8; ++nd) oacc[nd][j] *= resc;
    }
    // P -> per-wave LDS (swizzled), then read back as A-fragments
#pragma unroll
    for (int n = 0; n < 4; ++n)
#pragma unroll
      for (int j = 0; j < 4; ++j) {
        int q = lg * 4 + j;
        int k = n * 16 + lr;
        Pl[w][(q << 6) + ((((k >> 3) ^ q) & 7) << 3) + (k & 7)] = f2bf(p[n][j]);
      }
#pragma unroll
    for (int ks = 0; ks < 2; ++ks) {
      int kg = ks * 4 + lg;
      bf16x8 pF = *(const bf16x8*)&Pl[w][(lr << 6) + (((kg ^ lr) & 7) << 3)];
#pragma unroll
      for (int nd = 0; nd < 8; ++nd) {
        int d = nd * 16 + lr;
        bf16x8 vF = *(const bf16x8*)&Vs[(d << 6) + (((kg ^ d) & 7) << 3)];
        oacc[nd] = __builtin_amdgcn_mfma_f32_16x16x32_bf16(pF, vF, oacc[nd], 0, 0, 0);
      }
    }
  }
  float inv[4];
#pragma unroll
  for (int j = 0; j < 4; ++j) inv[j] = 1.0f / lsum[j];
#pragma unroll
  for (int nd = 0; nd < 8; ++nd)
#pragma unroll
    for (int j = 0; j < 4; ++j) {
      int row = qb0 + w * 16 + lg * 4 + j;
      int col = h * 128 + nd * 16 + lr;
      O[(size_t)row * DIMN + col] = f2bf(oacc[nd][j] * inv[j]);
    }
}

// ---------------------------------------------------------------------------
extern "C" void kernel_launch(void* const* d_in, const int* in_sizes, int n_in,
                              void* d_out, int out_size, void* d_ws, size_t ws_size,
                              hipStream_t stream)
{
  (void)in_sizes; (void)n_in; (void)out_size; (void)ws_size;
  const float* x          = (const float*)d_in[0];
  const int*   ids        = (const int*)d_in[1];
  const int*   wptr       = (const int*)d_in[2];
  const float* anw        = (const float*)d_in[3];
  const float* attn_scale = (const float*)d_in[14];
  const float* q_gain     = (const float*)d_in[15];
  const float* vemb       = (const float*)d_in[16];
  const float* vpB        = (const float*)d_in[17];
  const float* mnw        = (const float*)d_in[19];
  const float* mlp_scale  = (const float*)d_in[24];

  char* ws = (char*)d_ws;
  u16* W16 = (u16*)ws;
  static const int WOFF[16] = {0, 524288, 1048576, 1572864, 1638400, 1703936,
                               1835008, 1966080, 2097152, 2621440, 3145728,
                               3162112, 3424256, 4472832, 5521408, 5783552};
  const u16* qB16   = W16 + WOFF[0];
  const u16* qA16   = W16 + WOFF[1];
  const u16* kvB16  = W16 + WOFF[2];
  const u16* kvA16  = W16 + WOFF[3];
  const u16* kuB16  = W16 + WOFF[4];
  const u16* kuA16  = W16 + WOFF[5];
  const u16* vuB16  = W16 + WOFF[6];
  const u16* vuA16  = W16 + WOFF[7];
  const u16* oB16   = W16 + WOFF[8];
  const u16* oA16   = W16 + WOFF[9];
  const u16* vpA16  = W16 + WOFF[10];
  const u16* fcB16  = W16 + WOFF[11];
  const u16* fcA16  = W16 + WOFF[12];
  const u16* fc2B16 = W16 + WOFF[13];
  const u16* fc2A16 = W16 + WOFF[14];

  u16*   xa16  = (u16*)(ws + (size_t)(12u) * 1048576);   // also reused for u16 (mlp norm)
  u16*   rbA   = (u16*)(ws + (size_t)(20u) * 1048576);   // rank buffer 2048x256 bf16
  u16*   z16   = (u16*)(ws + (size_t)(21u) * 1048576);   // z (2048x256); later t16 (2048x32)
  u16*   k16   = (u16*)(ws + (size_t)(22u) * 1048576);
  float* v32   = (float*)(ws + (size_t)(24u) * 1048576);
  u16*   vt16  = (u16*)(ws + (size_t)(28u) * 1048576);
  u16*   q16   = (u16*)(ws + (size_t)(30u) * 1048576);
  u16*   ao16  = (u16*)(ws + (size_t)(38u) * 1048576);
  float* parts = (float*)(ws + (size_t)(46u) * 1048576); // 16MB: splitK parts / o32 / f2
  u16*   h16   = (u16*)(ws + (size_t)(62u) * 1048576);   // 32MB
  float* x2    = (float*)d_out;

  ConvArgs ca;
  const int widx[15] = {4, 5, 6, 7, 8, 9, 10, 11, 12, 13, 18, 20, 21, 22, 23};
  for (int i = 0; i < 15; ++i) ca.s[i] = (const float*)d_in[widx[i]];
  for (int i = 0; i < 16; ++i) ca.off[i] = WOFF[i];

  conv_weights<<<(5783552 + 255) / 256, 256, 0, stream>>>(ca, W16, 5783552);
  rmsnorm_k<<<2048, 256, 0, stream>>>(x, anw, xa16, 1e-6f);

  // q = xa @ qB.T @ qA.T
  gemm_nt<64, 0><<<dim3(16, 2, 8), 256, 0, stream>>>(xa16, qB16, parts, 2048, 256, 2048);
  redcvt_k<<<2048, 256, 0, stream>>>(parts, rbA, 524288, 8);
  gemm_nt<64, 1><<<dim3(16, 16, 1), 256, 0, stream>>>(rbA, qA16, q16, 2048, 2048, 256);
  // z = xa @ kvB.T @ kvA.T
  gemm_nt<64, 0><<<dim3(16, 2, 8), 256, 0, stream>>>(xa16, kvB16, parts, 2048, 256, 2048);
  redcvt_k<<<2048, 256, 0, stream>>>(parts, rbA, 524288, 8);
  gemm_nt<64, 1><<<dim3(16, 2, 1), 256, 0, stream>>>(rbA, kvA16, z16, 2048, 256, 256);
  // k = z @ kuB.T @ kuA.T
  gemm_nt<64, 1><<<dim3(16, 2, 1), 256, 0, stream>>>(z16, kuB16, rbA, 2048, 256, 256);
  gemm_nt<64, 1><<<dim3(16, 4, 1), 256, 0, stream>>>(rbA, kuA16, k16, 2048, 512, 256);
  // v = z @ vuB.T @ vuA.T  (f32)
  gemm_nt<64, 1><<<dim3(16, 2, 1), 256, 0, stream>>>(z16, vuB16, rbA, 2048, 256, 256);
  gemm_nt<64, 0><<<dim3(16, 4, 1), 256, 0, stream>>>(rbA, vuA16, v32, 2048, 512, 256);
  // v += lr(value_emb[ids], vpB, vpA)
  g9_k<<<256, 256, 0, stream>>>(ids, vemb, vpB, z16 /* t16 reuse */);
  gemm_nt<32, 3><<<dim3(16, 4, 1), 256, 0, stream>>>(z16, vpA16, v32, 2048, 512, 32);
  vtprep_k<<<4096, 256, 0, stream>>>(v32, vt16);
  // head norms / rope / gain
  qkproc_k<<<dim3(2048, 4), 256, 0, stream>>>(q16, 2048, q_gain, 1);
  qkproc_k<<<dim3(2048, 1), 256, 0, stream>>>(k16, 512, nullptr, 0);
  // attention
  attn_kernel<<<dim3(32, 16), 256, 0, stream>>>(q16, k16, vt16, ao16, wptr);
  // o = attn_out @ oB.T @ oA.T (f32), x2 = x + attn_scale*o
  gemm_nt<64, 0><<<dim3(16, 2, 8), 256, 0, stream>>>(ao16, oB16, parts, 2048, 256, 2048);
  redcvt_k<<<2048, 256, 0, stream>>>(parts, rbA, 524288, 8);
  gemm_nt<64, 0><<<dim3(16, 16, 1), 256, 0, stream>>>(rbA, oA16, parts, 2048, 2048, 256);
  resid_k<<<4096, 256, 0, stream>>>(x, parts, attn_scale, x2);
  // mlp
  rmsnorm_k<<<2048, 256, 0, stream>>>(x2, mnw, xa16, 1e-6f);
  gemm_nt<64, 0><<<dim3(16, 1, 8), 256, 0, stream>>>(xa16, fcB16, parts, 2048, 128, 2048);
  redcvt_k<<<1024, 256, 0, stream>>>(parts, rbA, 262144, 8);
  gemm_nt<64, 2><<<dim3(16, 64, 1), 256, 0, stream>>>(rbA, fcA16, h16, 2048, 8192, 128);
  gemm_nt<64, 0><<<dim3(16, 1, 16), 256, 0, stream>>>(h16, fc2B16, parts, 2048, 128, 8192);
  redcvt_k<<<1024, 256, 0, stream>>>(parts, rbA, 262144, 16);
  gemm_nt<64, 0><<<dim3(16, 16, 1), 256, 0, stream>>>(rbA, fc2A16, parts, 2048, 2048, 128);
  resid_k<<<4096, 256, 0, stream>>>(x2, parts, mlp_scale, x2);
}

// Round 2
// 282.178 us; speedup vs baseline: 1.0064x; 1.0064x over previous
//
#include <hip/hip_runtime.h>
#include <cstdint>
#include <cstddef>

typedef unsigned short u16;
typedef __attribute__((ext_vector_type(4))) float f32x4;
typedef __attribute__((ext_vector_type(8))) short bf16x8;

#define SEQT 2048
#define DIMN 2048

__device__ __forceinline__ float bf2f(u16 h){
  union { unsigned int u; float f; } v; v.u = ((unsigned int)h) << 16; return v.f;
}
__device__ __forceinline__ u16 f2bf(float f){
  union { float f; unsigned int u; } v; v.f = f;
  unsigned int r = v.u + 0x7fffu + ((v.u >> 16) & 1u);
  return (u16)(r >> 16);
}

typedef const __attribute__((address_space(1))) unsigned int* gas1_t;
typedef __attribute__((address_space(3))) unsigned int* las3_t;
__device__ __forceinline__ void gload_lds16(const void* g, void* l){
  __builtin_amdgcn_global_load_lds((gas1_t)g, (las3_t)l, 16, 0, 0);
}

// ---------------------------------------------------------------------------
// Generic NT GEMM: C[m,n] = sum_k A[m,k]*B[n,k], A:(M,K) bf16, B:(N,K) bf16.
// BM=128, BN=128 fixed; 256 threads = 4 waves in 2x2, each 64x64 (4x4 frags).
// Split-K via gridDim.z (EPI=0 only): block z writes partial to C + z*M*N.
// EPI: 0 = f32 store, 1 = bf16 store, 2 = relu^2 -> bf16, 3 = f32 add-into.
// ---------------------------------------------------------------------------
template<int BK, int EPI>
__global__ __launch_bounds__(256, 2) void gemm_nt(
    const u16* __restrict__ A, const u16* __restrict__ B, void* __restrict__ Cv,
    int M, int N, int K)
{
  __shared__ u16 As[128 * BK];
  __shared__ u16 Bs[128 * BK];
  constexpr int ITER = (128 * BK) / 2048;
  constexpr int GM = BK / 8 - 1;
  const int t = threadIdx.x;
  const int w = t >> 6, l = t & 63;
  const int lr = l & 15, lg = l >> 4;
  const int brow = blockIdx.x << 7, bcol = blockIdx.y << 7;
  const int wr = (w >> 1) << 6, wc = (w & 1) << 6;
  const int Kc = K / gridDim.z;
  const int kbeg = blockIdx.z * Kc;
  const int kend = kbeg + Kc;
  f32x4 acc[4][4] = {};
  for (int k0 = kbeg; k0 < kend; k0 += BK) {
    __syncthreads();
#pragma unroll
    for (int i = 0; i < ITER; ++i) {
      int eo = i * 2048 + t * 8;
      int row = eo / BK;
      int cg = (eo & (BK - 1)) >> 3;
      int scol = ((cg ^ row) & GM) << 3;       // pre-swizzled global source
      gload_lds16(A + (size_t)(brow + row) * K + k0 + scol, &As[eo]);
      gload_lds16(B + (size_t)(bcol + row) * K + k0 + scol, &Bs[eo]);
    }
    __syncthreads();
#pragma unroll
    for (int ks = 0; ks < BK / 32; ++ks) {
      bf16x8 aF[4], bF[4];
#pragma unroll
      for (int m = 0; m < 4; ++m) {
        int row = wr + m * 16 + lr;
        int kg = ks * 4 + lg;
        aF[m] = *(const bf16x8*)&As[row * BK + (((kg ^ row) & GM) << 3)];
      }
#pragma unroll
      for (int n = 0; n < 4; ++n) {
        int row = wc + n * 16 + lr;
        int kg = ks * 4 + lg;
        bF[n] = *(const bf16x8*)&Bs[row * BK + (((kg ^ row) & GM) << 3)];
      }
#pragma unroll
      for (int m = 0; m < 4; ++m)
#pragma unroll
        for (int n = 0; n < 4; ++n)
          acc[m][n] = __builtin_amdgcn_mfma_f32_16x16x32_bf16(aF[m], bF[n], acc[m][n], 0, 0, 0);
    }
  }
  const size_t zoff = (size_t)blockIdx.z * (size_t)M * (size_t)N;
#pragma unroll
  for (int m = 0; m < 4; ++m)
#pragma unroll
    for (int n = 0; n < 4; ++n)
#pragma unroll
      for (int j = 0; j < 4; ++j) {
        int row = brow + wr + m * 16 + lg * 4 + j;
        int col = bcol + wc + n * 16 + lr;
        float v = acc[m][n][j];
        if constexpr (EPI == 0) ((float*)Cv)[zoff + (size_t)row * N + col] = v;
        else if constexpr (EPI == 1) ((u16*)Cv)[(size_t)row * N + col] = f2bf(v);
        else if constexpr (EPI == 2) { float r = v > 0.f ? v * v : 0.f; ((u16*)Cv)[(size_t)row * N + col] = f2bf(r); }
        else ((float*)Cv)[(size_t)row * N + col] += v;
      }
}

// Sum split-K partials -> bf16
__global__ __launch_bounds__(256) void redcvt_k(const float* __restrict__ parts,
                                                u16* __restrict__ out, int n, int S)
{
  int i = blockIdx.x * 256 + threadIdx.x;
  if (i >= n) return;
  float s = 0.f;
  for (int z = 0; z < S; ++z) s += parts[(size_t)z * n + i];
  out[i] = f2bf(s);
}

// ---------------------------------------------------------------------------
// Weight f32 -> bf16 conversion (all weights packed into one dest region)
// ---------------------------------------------------------------------------
struct ConvArgs { const float* s[15]; int off[16]; };
__global__ __launch_bounds__(256) void conv_weights(ConvArgs a, u16* __restrict__ dst, int total)
{
  int i = blockIdx.x * 256 + threadIdx.x;
  if (i >= total) return;
  int seg = 0;
#pragma unroll
  for (int k = 1; k < 15; ++k) if (i >= a.off[k]) seg = k;
  dst[i] = f2bf(a.s[seg][i - a.off[seg]]);
}

// rmsnorm over DIM=2048, f32 in -> bf16 out (with weight)
__global__ __launch_bounds__(256) void rmsnorm_k(const float* __restrict__ x,
                                                 const float* __restrict__ wg,
                                                 u16* __restrict__ o, float eps)
{
  int row = blockIdx.x;
  const float* xr = x + (size_t)row * DIMN;
  float v[8]; float ss = 0.f;
#pragma unroll
  for (int i = 0; i < 8; ++i) { v[i] = xr[threadIdx.x + i * 256]; ss += v[i] * v[i]; }
#pragma unroll
  for (int m = 1; m < 64; m <<= 1) ss += __shfl_xor(ss, m);
  __shared__ float red[4];
  if ((threadIdx.x & 63) == 0) red[threadIdx.x >> 6] = ss;
  __syncthreads();
  float tot = red[0] + red[1] + red[2] + red[3];
  float rs = rsqrtf(tot * (1.0f / DIMN) + eps);
  u16* orow = o + (size_t)row * DIMN;
#pragma unroll
  for (int i = 0; i < 8; ++i) { int c = threadIdx.x + i * 256; orow[c] = f2bf(v[i] * rs * wg[c]); }
}

// per-head rms (HEPS), optional RoPE (first 64 dims), optional gain; in-place bf16
// When gain path is active (q), also folds in the 1/sqrt(HD) attention scale.
__global__ __launch_bounds__(256) void qkproc_k(u16* __restrict__ qk, int rowstride,
                                                const float* __restrict__ gain, int do_rope)
{
  int tpos = blockIdx.x;
  int hh = blockIdx.y * 4 + (threadIdx.x >> 6);
  int l = threadIdx.x & 63;
  u16* p = qk + (size_t)tpos * rowstride + hh * 128;
  float v0 = bf2f(p[l]), v1 = bf2f(p[l + 64]);
  float ss = v0 * v0 + v1 * v1;
#pragma unroll
  for (int m = 1; m < 64; m <<= 1) ss += __shfl_xor(ss, m);
  float rs = rsqrtf(ss * (1.0f / 128.0f) + 1.1920929e-07f);
  v0 *= rs; v1 *= rs;
  if (do_rope) {
    int i = l & 31;
    float fr = __expf(-(float)i * 0.28782313662425574f); // ln(10000)/32
    float f = (float)tpos * fr;
    float c = cosf(f), sn = sinf(f);
    float o = __shfl_xor(v0, 32);
    v0 = (l < 32) ? (v0 * c + o * sn) : (v0 * c - o * sn);
  }
  if (gain) {
    float g = gain[hh] * 0.08838834764831845f;  // fold 128^-0.5 into q
    v0 *= g; v1 *= g;
  }
  p[l] = f2bf(v0); p[l + 64] = f2bf(v1);
}

// t16[2048][32] = value_emb[ids] @ vpB.T   (f32 inputs, bf16 out)
__global__ __launch_bounds__(256) void g9_k(const int* __restrict__ ids,
                                            const float* __restrict__ emb,
                                            const float* __restrict__ vpB,
                                            u16* __restrict__ t16)
{
  int idx = blockIdx.x * 256 + threadIdx.x;   // 2048*32
  int m = idx >> 5, n = idx & 31;
  int id = ids[m]; id = id < 0 ? 0 : (id > 50256 ? 50256 : id);
  const float* e = emb + (size_t)id * 64;
  const float* wr = vpB + n * 64;
  float s = 0.f;
#pragma unroll
  for (int k = 0; k < 64; ++k) s += e[k] * wr[k];
  t16[idx] = f2bf(s);
}

// vt[kh][d][t] = bf16(v32[t][kh*128+d])
__global__ __launch_bounds__(256) void vtprep_k(const float* __restrict__ v32, u16* __restrict__ vt)
{
  int o = blockIdx.x * 256 + threadIdx.x;     // 2048*512
  int kh = o >> 18, d = (o >> 11) & 127, tp = o & 2047;
  vt[o] = f2bf(v32[(size_t)tp * 512 + kh * 128 + d]);
}

// out = x + scale[col] * g   (f32, vectorized float4)
__global__ __launch_bounds__(256) void resid_k(const float* __restrict__ xin,
                                               const float* __restrict__ gin,
                                               const float* __restrict__ sc,
                                               float* __restrict__ out)
{
  int i = blockIdx.x * 256 + threadIdx.x;     // float4 index
  float4 xv = ((const float4*)xin)[i];
  float4 gv = ((const float4*)gin)[i];
  float4 sv = ((const float4*)sc)[i & (DIMN / 4 - 1)];
  float4 ov;
  ov.x = xv.x + sv.x * gv.x; ov.y = xv.y + sv.y * gv.y;
  ov.z = xv.z + sv.z * gv.z; ov.w = xv.w + sv.w * gv.w;
  ((float4*)out)[i] = ov;
}

// ---------------------------------------------------------------------------
// Flash attention, sliding window, SPLIT-KV, static max (q,k rms-normed so
// scores are bounded: |s| <= sqrt(128)*gain -> exp never overflows f32).
// Grid (qb=32, head=16, chunk=3). Each chunk handles ~nt/3 of the KV tiles
// and writes unnormalized O-partial (f32) + row-sum l to scratch; a merge
// kernel sums chunks and normalizes. No running max, no rescale.
// ---------------------------------------------------------------------------
__device__ __forceinline__ int read_window(const int* wptr){
  int W = *wptr;
  if (W > 65536 || W < 0) { union { int i; float f; } u; u.i = W; W = (int)u.f; }
  if (W < 1) W = 1;
  if (W > SEQT) W = SEQT;
  return W;
}

__global__ __launch_bounds__(256, 2) void attn_part(
    const u16* __restrict__ Q, const u16* __restrict__ Kx, const u16* __restrict__ Vt,
    float* __restrict__ Opart, float* __restrict__ Lpart, const int* __restrict__ wptr)
{
  __shared__ u16 Ks[64 * 128];
  __shared__ u16 Vs[128 * 64];
  __shared__ u16 Pl[4][16 * 64];
  const int t = threadIdx.x;
  const int w = t >> 6, l = t & 63;
  const int lr = l & 15, lg = l >> 4;
  const int h = blockIdx.y, kh = h >> 2;
  const int qb = blockIdx.x, qb0 = qb << 6;
  const int c = blockIdx.z;
  const int W = read_window(wptr);
  int kstart = qb0 - W + 1;
  if (kstart < 0) kstart = 0;
  kstart &= ~63;
  const int nt = ((qb0 - kstart) >> 6) + 1;
  const int tb = (c * nt) / 3, te = ((c + 1) * nt) / 3;
  if (tb >= te) return;
  bf16x8 qF[4];
  {
    const u16* qbp = Q + (size_t)(qb0 + w * 16 + lr) * DIMN + h * 128;
#pragma unroll
    for (int ks = 0; ks < 4; ++ks) qF[ks] = *(const bf16x8*)(qbp + ks * 32 + lg * 8);
  }
  f32x4 oacc[8] = {};
  float lsum[4] = {0.f, 0.f, 0.f, 0.f};
  for (int tt = tb; tt < te; ++tt) {
    const int kc = kstart + (tt << 6);
    __syncthreads();
#pragma unroll
    for (int i = 0; i < 4; ++i) {
      int eo = i * 2048 + t * 8;
      {
        int row = eo >> 7, cg = (eo >> 3) & 15;
        gload_lds16(Kx + (size_t)(kc + row) * 512 + kh * 128 + (((cg ^ row) & 15) << 3), &Ks[eo]);
      }
      {
        int d = eo >> 6, kg = (eo >> 3) & 7;
        gload_lds16(Vt + (size_t)kh * (128 * SEQT) + (size_t)d * SEQT + kc + (((kg ^ d) & 7) << 3), &Vs[eo]);
      }
    }
    __syncthreads();
    f32x4 sf[4] = {};
#pragma unroll
    for (int ks = 0; ks < 4; ++ks) {
#pragma unroll
      for (int n = 0; n < 4; ++n) {
        int row = n * 16 + lr;
        int kg = ks * 4 + lg;
        bf16x8 kF = *(const bf16x8*)&Ks[(row << 7) + (((kg ^ row) & 15) << 3)];
        sf[n] = __builtin_amdgcn_mfma_f32_16x16x32_bf16(qF[ks], kF, sf[n], 0, 0, 0);
      }
    }
    // mask + exp (scores already scaled via q); accumulate row-sums per lane
#pragma unroll
    for (int j = 0; j < 4; ++j) {
      int qi = qb0 + w * 16 + lg * 4 + j;
      float pr = 0.f;
#pragma unroll
      for (int n = 0; n < 4; ++n) {
        int kj = kc + n * 16 + lr;
        bool valid = (kj <= qi) && ((qi - kj) < W);
        float pv = valid ? __expf(sf[n][j]) : 0.f;
        sf[n][j] = pv;
        pr += pv;
      }
      lsum[j] += pr;
    }
    // P -> per-wave LDS (swizzled), then read back as A-fragments
#pragma unroll
    for (int n = 0; n < 4; ++n)
#pragma unroll
      for (int j = 0; j < 4; ++j) {
        int q = lg * 4 + j;
        int k = n * 16 + lr;
        Pl[w][(q << 6) + ((((k >> 3) ^ q) & 7) << 3) + (k & 7)] = f2bf(sf[n][j]);
      }
#pragma unroll
    for (int ks = 0; ks < 2; ++ks) {
      int kg = ks * 4 + lg;
      bf16x8 pF = *(const bf16x8*)&Pl[w][(lr << 6) + (((kg ^ lr) & 7) << 3)];
#pragma unroll
      for (int nd = 0; nd < 8; ++nd) {
        int d = nd * 16 + lr;
        bf16x8 vF = *(const bf16x8*)&Vs[(d << 6) + (((kg ^ d) & 7) << 3)];
        oacc[nd] = __builtin_amdgcn_mfma_f32_16x16x32_bf16(pF, vF, oacc[nd], 0, 0, 0);
      }
    }
  }
  // write partials
  const size_t obase = ((size_t)(h * 32 + qb) * 3 + c) * 8192;
  const size_t lbase = ((size_t)(h * 32 + qb) * 3 + c) * 64;
  // reduce lsum across the 16 lanes of each k-group
#pragma unroll
  for (int j = 0; j < 4; ++j) {
    float s = lsum[j];
#pragma unroll
    for (int mm = 1; mm < 16; mm <<= 1) s += __shfl_xor(s, mm);
    if (lr == 0) Lpart[lbase + w * 16 + lg * 4 + j] = s;
  }
#pragma unroll
  for (int nd = 0; nd < 8; ++nd)
#pragma unroll
    for (int j = 0; j < 4; ++j) {
      int row = w * 16 + lg * 4 + j;
      int col = nd * 16 + lr;
      Opart[obase + (size_t)row * 128 + col] = oacc[nd][j];
    }
}

__global__ __launch_bounds__(256) void attn_merge(
    const float* __restrict__ Opart, const float* __restrict__ Lpart,
    u16* __restrict__ O, const int* __restrict__ wptr)
{
  const int qb = blockIdx.x, h = blockIdx.y, qb0 = qb << 6;
  const int W = read_window(wptr);
  int kstart = qb0 - W + 1;
  if (kstart < 0) kstart = 0;
  kstart &= ~63;
  const int nt = ((qb0 - kstart) >> 6) + 1;
  const size_t obase = (size_t)(h * 32 + qb) * 3 * 8192;
  const size_t lbase = (size_t)(h * 32 + qb) * 3 * 64;
  bool v0 = (0 * nt) / 3 < (1 * nt) / 3;
  bool v1 = (1 * nt) / 3 < (2 * nt) / 3;
  bool v2 = (2 * nt) / 3 < nt;
#pragma unroll
  for (int i = 0; i < 8; ++i) {
    int idx4 = threadIdx.x + (i << 8);        // 0..2047 float4 slots (64x32)
    int r = idx4 >> 5, c4 = idx4 & 31;
    float4 acc = make_float4(0.f, 0.f, 0.f, 0.f);
    float ls = 0.f;
#pragma unroll
    for (int c = 0; c < 3; ++c) {
      bool valid = c == 0 ? v0 : (c == 1 ? v1 : v2);
      if (valid) {
        float4 vv = *((const float4*)(Opart + obase + (size_t)c * 8192 + r * 128) + c4);
        acc.x += vv.x; acc.y += vv.y; acc.z += vv.z; acc.w += vv.w;
        ls += Lpart[lbase + c * 64 + r];
      }
    }
    float inv = 1.0f / ls;
    u16 o0 = f2bf(acc.x * inv), o1 = f2bf(acc.y * inv);
    u16 o2 = f2bf(acc.z * inv), o3 = f2bf(acc.w * inv);
    unsigned int lo = (unsigned int)o0 | ((unsigned int)o1 << 16);
    unsigned int hi = (unsigned int)o2 | ((unsigned int)o3 << 16);
    uint2 pk; pk.x = lo; pk.y = hi;
    *(uint2*)&O[(size_t)(qb0 + r) * DIMN + h * 128 + c4 * 4] = pk;
  }
}

// ---------------------------------------------------------------------------
extern "C" void kernel_launch(void* const* d_in, const int* in_sizes, int n_in,
                              void* d_out, int out_size, void* d_ws, size_t ws_size,
                              hipStream_t stream)
{
  (void)in_sizes; (void)n_in; (void)out_size; (void)ws_size;
  const float* x          = (const float*)d_in[0];
  const int*   ids        = (const int*)d_in[1];
  const int*   wptr       = (const int*)d_in[2];
  const float* anw        = (const float*)d_in[3];
  const float* attn_scale = (const float*)d_in[14];
  const float* q_gain     = (const float*)d_in[15];
  const float* vemb       = (const float*)d_in[16];
  const float* vpB        = (const float*)d_in[17];
  const float* mnw        = (const float*)d_in[19];
  const float* mlp_scale  = (const float*)d_in[24];

  char* ws = (char*)d_ws;
  u16* W16 = (u16*)ws;
  static const int WOFF[16] = {0, 524288, 1048576, 1572864, 1638400, 1703936,
                               1835008, 1966080, 2097152, 2621440, 3145728,
                               3162112, 3424256, 4472832, 5521408, 5783552};
  const u16* qB16   = W16 + WOFF[0];
  const u16* qA16   = W16 + WOFF[1];
  const u16* kvB16  = W16 + WOFF[2];
  const u16* kvA16  = W16 + WOFF[3];
  const u16* kuB16  = W16 + WOFF[4];
  const u16* kuA16  = W16 + WOFF[5];
  const u16* vuB16  = W16 + WOFF[6];
  const u16* vuA16  = W16 + WOFF[7];
  const u16* oB16   = W16 + WOFF[8];
  const u16* oA16   = W16 + WOFF[9];
  const u16* vpA16  = W16 + WOFF[10];
  const u16* fcB16  = W16 + WOFF[11];
  const u16* fcA16  = W16 + WOFF[12];
  const u16* fc2B16 = W16 + WOFF[13];
  const u16* fc2A16 = W16 + WOFF[14];

  u16*   xa16  = (u16*)(ws + (size_t)(12u) * 1048576);   // also reused for u (mlp norm)
  u16*   rbA   = (u16*)(ws + (size_t)(20u) * 1048576);   // rank buffer 2048x256 bf16
  u16*   z16   = (u16*)(ws + (size_t)(21u) * 1048576);   // z (2048x256); later t16 (2048x32)
  u16*   k16   = (u16*)(ws + (size_t)(22u) * 1048576);
  float* v32   = (float*)(ws + (size_t)(24u) * 1048576);
  u16*   vt16  = (u16*)(ws + (size_t)(28u) * 1048576);
  u16*   q16   = (u16*)(ws + (size_t)(30u) * 1048576);
  u16*   ao16  = (u16*)(ws + (size_t)(38u) * 1048576);
  float* parts = (float*)(ws + (size_t)(46u) * 1048576); // 16MB splitK parts
  u16*   h16   = (u16*)(ws + (size_t)(62u) * 1048576);   // 32MB
  // attn partials overlay parts+h16 region (not live simultaneously)
  float* Lpart = (float*)(ws + (size_t)(46u) * 1048576); // 384KB (aliases parts pre-attn use: ok, attn runs before o-proj gemms)
  float* Opart = (float*)(ws + (size_t)(47u) * 1048576); // 50.4MB -> ends ~97.4MB
  float* x2    = (float*)d_out;

  ConvArgs ca;
  const int widx[15] = {4, 5, 6, 7, 8, 9, 10, 11, 12, 13, 18, 20, 21, 22, 23};
  for (int i = 0; i < 15; ++i) ca.s[i] = (const float*)d_in[widx[i]];
  for (int i = 0; i < 16; ++i) ca.off[i] = WOFF[i];

  conv_weights<<<(5783552 + 255) / 256, 256, 0, stream>>>(ca, W16, 5783552);
  rmsnorm_k<<<2048, 256, 0, stream>>>(x, anw, xa16, 1e-6f);

  // q = xa @ qB.T @ qA.T
  gemm_nt<64, 0><<<dim3(16, 2, 8), 256, 0, stream>>>(xa16, qB16, parts, 2048, 256, 2048);
  redcvt_k<<<2048, 256, 0, stream>>>(parts, rbA, 524288, 8);
  gemm_nt<64, 1><<<dim3(16, 16, 1), 256, 0, stream>>>(rbA, qA16, q16, 2048, 2048, 256);
  // z = xa @ kvB.T @ kvA.T
  gemm_nt<64, 0><<<dim3(16, 2, 8), 256, 0, stream>>>(xa16, kvB16, parts, 2048, 256, 2048);
  redcvt_k<<<2048, 256, 0, stream>>>(parts, rbA, 524288, 8);
  gemm_nt<64, 1><<<dim3(16, 2, 1), 256, 0, stream>>>(rbA, kvA16, z16, 2048, 256, 256);
  // k = z @ kuB.T @ kuA.T
  gemm_nt<64, 1><<<dim3(16, 2, 1), 256, 0, stream>>>(z16, kuB16, rbA, 2048, 256, 256);
  gemm_nt<64, 1><<<dim3(16, 4, 1), 256, 0, stream>>>(rbA, kuA16, k16, 2048, 512, 256);
  // v = z @ vuB.T @ vuA.T  (f32)
  gemm_nt<64, 1><<<dim3(16, 2, 1), 256, 0, stream>>>(z16, vuB16, rbA, 2048, 256, 256);
  gemm_nt<64, 0><<<dim3(16, 4, 1), 256, 0, stream>>>(rbA, vuA16, v32, 2048, 512, 256);
  // v += lr(value_emb[ids], vpB, vpA)
  g9_k<<<256, 256, 0, stream>>>(ids, vemb, vpB, z16 /* t16 reuse */);
  gemm_nt<32, 3><<<dim3(16, 4, 1), 256, 0, stream>>>(z16, vpA16, v32, 2048, 512, 32);
  vtprep_k<<<4096, 256, 0, stream>>>(v32, vt16);
  // head norms / rope / gain (+1/sqrt(HD) folded into q)
  qkproc_k<<<dim3(2048, 4), 256, 0, stream>>>(q16, 2048, q_gain, 1);
  qkproc_k<<<dim3(2048, 1), 256, 0, stream>>>(k16, 512, nullptr, 0);
  // attention: split-KV partials + merge
  attn_part<<<dim3(32, 16, 3), 256, 0, stream>>>(q16, k16, vt16, Opart, Lpart, wptr);
  attn_merge<<<dim3(32, 16), 256, 0, stream>>>(Opart, Lpart, ao16, wptr);
  // o = attn_out @ oB.T @ oA.T (f32), x2 = x + attn_scale*o
  gemm_nt<64, 0><<<dim3(16, 2, 8), 256, 0, stream>>>(ao16, oB16, parts, 2048, 256, 2048);
  redcvt_k<<<2048, 256, 0, stream>>>(parts, rbA, 524288, 8);
  gemm_nt<64, 0><<<dim3(16, 16, 1), 256, 0, stream>>>(rbA, oA16, parts, 2048, 2048, 256);
  resid_k<<<4096, 256, 0, stream>>>(x, parts, attn_scale, x2);
  // mlp
  rmsnorm_k<<<2048, 256, 0, stream>>>(x2, mnw, xa16, 1e-6f);
  gemm_nt<64, 0><<<dim3(16, 1, 8), 256, 0, stream>>>(xa16, fcB16, parts, 2048, 128, 2048);
  redcvt_k<<<1024, 256, 0, stream>>>(parts, rbA, 262144, 8);
  gemm_nt<64, 2><<<dim3(16, 64, 1), 256, 0, stream>>>(rbA, fcA16, h16, 2048, 8192, 128);
  gemm_nt<64, 0><<<dim3(16, 1, 16), 256, 0, stream>>>(h16, fc2B16, parts, 2048, 128, 8192);
  redcvt_k<<<1024, 256, 0, stream>>>(parts, rbA, 262144, 16);
  gemm_nt<64, 0><<<dim3(16, 16, 1), 256, 0, stream>>>(rbA, fc2A16, parts, 2048, 2048, 128);
  resid_k<<<4096, 256, 0, stream>>>(x2, parts, mlp_scale, x2);
}

// Round 3
// 238.603 us; speedup vs baseline: 1.1902x; 1.1826x over previous
//
#include <hip/hip_runtime.h>
#include <cstdint>
#include <cstddef>

typedef unsigned short u16;
typedef __attribute__((ext_vector_type(4))) float f32x4;
typedef __attribute__((ext_vector_type(8))) short bf16x8;

#define SEQT 2048
#define DIMN 2048

__device__ __forceinline__ float bf2f(u16 h){
  union { unsigned int u; float f; } v; v.u = ((unsigned int)h) << 16; return v.f;
}
__device__ __forceinline__ u16 f2bf(float f){
  union { float f; unsigned int u; } v; v.f = f;
  unsigned int r = v.u + 0x7fffu + ((v.u >> 16) & 1u);
  return (u16)(r >> 16);
}
__device__ __forceinline__ float fexp2(float x){
  float r;
  asm("v_exp_f32 %0, %1" : "=v"(r) : "v"(x));
  return r;
}
__device__ __forceinline__ unsigned int cvtpk(float lo, float hi){
  unsigned int r;
  asm("v_cvt_pk_bf16_f32 %0, %1, %2" : "=v"(r) : "v"(lo), "v"(hi));
  return r;
}

typedef const __attribute__((address_space(1))) unsigned int* gas1_t;
typedef __attribute__((address_space(3))) unsigned int* las3_t;
__device__ __forceinline__ void gload_lds16(const void* g, void* l){
  __builtin_amdgcn_global_load_lds((gas1_t)g, (las3_t)l, 16, 0, 0);
}

// ---------------------------------------------------------------------------
// Generic NT GEMM: C[m,n] = sum_k A[m,k]*B[n,k], A:(M,lda) bf16, B:(N,K) bf16.
// BM=128, BN=128; 256 threads = 4 waves 2x2, each 64x64 (4x4 frags).
// Split-K via gridDim.z (EPI=0 only).
// EPI: 0 f32 store (+z-offset), 1 bf16 store, 2 relu^2->bf16,
//      3 f32 add-into, 4 f32 out = Xres + SC[col]*acc (residual fuse).
// ---------------------------------------------------------------------------
template<int BK, int EPI>
__global__ __launch_bounds__(256, 2) void gemm_nt(
    const u16* __restrict__ A, const u16* __restrict__ B, void* __restrict__ Cv,
    int M, int N, int K, int lda, const float* __restrict__ Xres,
    const float* __restrict__ SC)
{
  __shared__ u16 As[128 * BK];
  __shared__ u16 Bs[128 * BK];
  constexpr int ITER = (128 * BK) / 2048;
  constexpr int GM = BK / 8 - 1;
  const int t = threadIdx.x;
  const int w = t >> 6, l = t & 63;
  const int lr = l & 15, lg = l >> 4;
  const int brow = blockIdx.x << 7, bcol = blockIdx.y << 7;
  const int wr = (w >> 1) << 6, wc = (w & 1) << 6;
  const int Kc = K / gridDim.z;
  const int kbeg = blockIdx.z * Kc;
  const int kend = kbeg + Kc;
  f32x4 acc[4][4] = {};
  for (int k0 = kbeg; k0 < kend; k0 += BK) {
    __syncthreads();
#pragma unroll
    for (int i = 0; i < ITER; ++i) {
      int eo = i * 2048 + t * 8;
      int row = eo / BK;
      int cg = (eo & (BK - 1)) >> 3;
      int scol = ((cg ^ row) & GM) << 3;       // pre-swizzled global source
      gload_lds16(A + (size_t)(brow + row) * lda + k0 + scol, &As[eo]);
      gload_lds16(B + (size_t)(bcol + row) * K + k0 + scol, &Bs[eo]);
    }
    __syncthreads();
#pragma unroll
    for (int ks = 0; ks < BK / 32; ++ks) {
      bf16x8 aF[4], bF[4];
#pragma unroll
      for (int m = 0; m < 4; ++m) {
        int row = wr + m * 16 + lr;
        int kg = ks * 4 + lg;
        aF[m] = *(const bf16x8*)&As[row * BK + (((kg ^ row) & GM) << 3)];
      }
#pragma unroll
      for (int n = 0; n < 4; ++n) {
        int row = wc + n * 16 + lr;
        int kg = ks * 4 + lg;
        bF[n] = *(const bf16x8*)&Bs[row * BK + (((kg ^ row) & GM) << 3)];
      }
#pragma unroll
      for (int m = 0; m < 4; ++m)
#pragma unroll
        for (int n = 0; n < 4; ++n)
          acc[m][n] = __builtin_amdgcn_mfma_f32_16x16x32_bf16(aF[m], bF[n], acc[m][n], 0, 0, 0);
    }
  }
  const size_t zoff = (size_t)blockIdx.z * (size_t)M * (size_t)N;
#pragma unroll
  for (int m = 0; m < 4; ++m)
#pragma unroll
    for (int n = 0; n < 4; ++n)
#pragma unroll
      for (int j = 0; j < 4; ++j) {
        int row = brow + wr + m * 16 + lg * 4 + j;
        int col = bcol + wc + n * 16 + lr;
        float v = acc[m][n][j];
        if constexpr (EPI == 0) ((float*)Cv)[zoff + (size_t)row * N + col] = v;
        else if constexpr (EPI == 1) ((u16*)Cv)[(size_t)row * N + col] = f2bf(v);
        else if constexpr (EPI == 2) { float r = v > 0.f ? v * v : 0.f; ((u16*)Cv)[(size_t)row * N + col] = f2bf(r); }
        else if constexpr (EPI == 3) ((float*)Cv)[(size_t)row * N + col] += v;
        else {
          float xo = Xres[(size_t)row * N + col];
          ((float*)Cv)[(size_t)row * N + col] = xo + SC[col] * v;
        }
      }
}

// Sum split-K partials -> bf16
__global__ __launch_bounds__(256) void redcvt_k(const float* __restrict__ parts,
                                                u16* __restrict__ out, int n, int S)
{
  int i = blockIdx.x * 256 + threadIdx.x;
  if (i >= n) return;
  float s = 0.f;
  for (int z = 0; z < S; ++z) s += parts[(size_t)z * n + i];
  out[i] = f2bf(s);
}

// ---------------------------------------------------------------------------
// Weight f32 -> bf16 conversion (all weights packed into one dest region)
// ---------------------------------------------------------------------------
struct ConvArgs { const float* s[15]; int off[16]; };
__global__ __launch_bounds__(256) void conv_weights(ConvArgs a, u16* __restrict__ dst, int total)
{
  int i = blockIdx.x * 256 + threadIdx.x;
  if (i >= total) return;
  int seg = 0;
#pragma unroll
  for (int k = 1; k < 15; ++k) if (i >= a.off[k]) seg = k;
  dst[i] = f2bf(a.s[seg][i - a.off[seg]]);
}

// rmsnorm over DIM=2048, f32 in -> bf16 out (with weight)
__global__ __launch_bounds__(256) void rmsnorm_k(const float* __restrict__ x,
                                                 const float* __restrict__ wg,
                                                 u16* __restrict__ o, float eps)
{
  int row = blockIdx.x;
  const float* xr = x + (size_t)row * DIMN;
  float v[8]; float ss = 0.f;
#pragma unroll
  for (int i = 0; i < 8; ++i) { v[i] = xr[threadIdx.x + i * 256]; ss += v[i] * v[i]; }
#pragma unroll
  for (int m = 1; m < 64; m <<= 1) ss += __shfl_xor(ss, m);
  __shared__ float red[4];
  if ((threadIdx.x & 63) == 0) red[threadIdx.x >> 6] = ss;
  __syncthreads();
  float tot = red[0] + red[1] + red[2] + red[3];
  float rs = rsqrtf(tot * (1.0f / DIMN) + eps);
  u16* orow = o + (size_t)row * DIMN;
#pragma unroll
  for (int i = 0; i < 8; ++i) { int c = threadIdx.x + i * 256; orow[c] = f2bf(v[i] * rs * wg[c]); }
}

// per-head rms (HEPS); q path (blockIdx.y<4): RoPE + gain*scale*log2e folded;
// k path (blockIdx.y==4): plain rms. One dispatch for both.
__global__ __launch_bounds__(256) void qkproc_k(u16* __restrict__ q, u16* __restrict__ k,
                                                const float* __restrict__ gain)
{
  int tpos = blockIdx.x;
  int y = blockIdx.y;
  int wi = threadIdx.x >> 6;
  int l = threadIdx.x & 63;
  u16* p; int do_rope; float gmul;
  if (y < 4) {
    int hh = y * 4 + wi;
    p = q + (size_t)tpos * 2048 + hh * 128;
    do_rope = 1;
    gmul = gain[hh] * 0.08838834764831845f * 1.4426950408889634f; // 1/sqrt(128)*log2(e)
  } else {
    p = k + (size_t)tpos * 512 + wi * 128;
    do_rope = 0;
    gmul = 1.0f;
  }
  float v0 = bf2f(p[l]), v1 = bf2f(p[l + 64]);
  float ss = v0 * v0 + v1 * v1;
#pragma unroll
  for (int m = 1; m < 64; m <<= 1) ss += __shfl_xor(ss, m);
  float rs = rsqrtf(ss * (1.0f / 128.0f) + 1.1920929e-07f);
  v0 *= rs; v1 *= rs;
  if (do_rope) {
    int i = l & 31;
    float fr = __expf(-(float)i * 0.28782313662425574f); // ln(10000)/32
    float f = (float)tpos * fr;
    float c = cosf(f), sn = sinf(f);
    float o = __shfl_xor(v0, 32);
    v0 = (l < 32) ? (v0 * c + o * sn) : (v0 * c - o * sn);
  }
  v0 *= gmul; v1 *= gmul;
  p[l] = f2bf(v0); p[l + 64] = f2bf(v1);
}

// t16[2048][32] = value_emb[ids] @ vpB.T   (f32 inputs, bf16 out)
__global__ __launch_bounds__(256) void g9_k(const int* __restrict__ ids,
                                            const float* __restrict__ emb,
                                            const float* __restrict__ vpB,
                                            u16* __restrict__ t16)
{
  int idx = blockIdx.x * 256 + threadIdx.x;   // 2048*32
  int m = idx >> 5, n = idx & 31;
  int id = ids[m]; id = id < 0 ? 0 : (id > 50256 ? 50256 : id);
  const float* e = emb + (size_t)id * 64;
  const float* wr = vpB + n * 64;
  float s = 0.f;
#pragma unroll
  for (int k = 0; k < 64; ++k) s += e[k] * wr[k];
  t16[idx] = f2bf(s);
}

// vt[kh][d][t] = bf16(v32[t][kh*128+d])
__global__ __launch_bounds__(256) void vtprep_k(const float* __restrict__ v32, u16* __restrict__ vt)
{
  int o = blockIdx.x * 256 + threadIdx.x;     // 2048*512
  int kh = o >> 18, d = (o >> 11) & 127, tp = o & 2047;
  vt[o] = f2bf(v32[(size_t)tp * 512 + kh * 128 + d]);
}

// ---------------------------------------------------------------------------
// Flash attention, sliding window, SPLIT-KV, SWAPPED-OPERAND QK^T.
// mfma(K,Q) -> S[k][q] with q lane-local: row-softmax sums are in-register,
// P packs to bf16 via cvt_pk (k-adjacent in regs), boundary-only masking,
// exp2 with log2e pre-folded into q. Static max (scores bounded ~16.3 in
// log2 domain after folding -> exp2 <= 8e4, sums < 8e7, f32-safe).
// ---------------------------------------------------------------------------
__device__ __forceinline__ int read_window(const int* wptr){
  int W = *wptr;
  if (W > 65536 || W < 0) { union { int i; float f; } u; u.i = W; W = (int)u.f; }
  if (W < 1) W = 1;
  if (W > SEQT) W = SEQT;
  return W;
}

__global__ __launch_bounds__(256, 2) void attn_part(
    const u16* __restrict__ Q, const u16* __restrict__ Kx, const u16* __restrict__ Vt,
    float* __restrict__ Opart, float* __restrict__ Lpart, const int* __restrict__ wptr)
{
  __shared__ u16 Ks[64 * 128];
  __shared__ u16 Vs[128 * 64];
  __shared__ u16 Pl[4][16 * 64];
  const int t = threadIdx.x;
  const int w = t >> 6, l = t & 63;
  const int lr = l & 15, lg = l >> 4;
  const int h = blockIdx.y, kh = h >> 2;
  const int qb = blockIdx.x, qb0 = qb << 6;
  const int c = blockIdx.z;
  const int W = read_window(wptr);
  int kstart = qb0 - W + 1;
  if (kstart < 0) kstart = 0;
  kstart &= ~63;
  const int nt = ((qb0 - kstart) >> 6) + 1;
  const int tb = (c * nt) / 3, te = ((c + 1) * nt) / 3;
  if (tb >= te) return;
  bf16x8 qF[4];
  {
    const u16* qbp = Q + (size_t)(qb0 + w * 16 + lr) * DIMN + h * 128;
#pragma unroll
    for (int ks = 0; ks < 4; ++ks) qF[ks] = *(const bf16x8*)(qbp + ks * 32 + lg * 8);
  }
  f32x4 oacc[8] = {};
  float lsum = 0.f;                      // per-lane: q=lr, this lg's k-slice
  const int qi = qb0 + w * 16 + lr;
  const int swz = (lr & 7) << 4;
  char* PlB = (char*)&Pl[w][0] + lr * 128;
  for (int tt = tb; tt < te; ++tt) {
    const int kc = kstart + (tt << 6);
    __syncthreads();
#pragma unroll
    for (int i = 0; i < 4; ++i) {
      int eo = i * 2048 + t * 8;
      {
        int row = eo >> 7, cg = (eo >> 3) & 15;
        gload_lds16(Kx + (size_t)(kc + row) * 512 + kh * 128 + (((cg ^ row) & 15) << 3), &Ks[eo]);
      }
      {
        int d = eo >> 6, kg = (eo >> 3) & 7;
        gload_lds16(Vt + (size_t)kh * (128 * SEQT) + (size_t)d * SEQT + kc + (((kg ^ d) & 7) << 3), &Vs[eo]);
      }
    }
    __syncthreads();
    // S^T = K·Q^T : sf[n][j] = S[k = kc+n*16+lg*4+j][q = qi]
    f32x4 sf[4] = {};
#pragma unroll
    for (int ks = 0; ks < 4; ++ks) {
#pragma unroll
      for (int n = 0; n < 4; ++n) {
        int row = n * 16 + lr;
        int kg = ks * 4 + lg;
        bf16x8 kF = *(const bf16x8*)&Ks[(row << 7) + (((kg ^ row) & 15) << 3)];
        sf[n] = __builtin_amdgcn_mfma_f32_16x16x32_bf16(kF, qF[ks], sf[n], 0, 0, 0);
      }
    }
    const bool fullv = ((kc + 63) <= (qb0 + w * 16)) &&
                       ((qb0 + w * 16 + 15 - kc) < W);
    if (fullv) {
#pragma unroll
      for (int n = 0; n < 4; ++n)
#pragma unroll
        for (int j = 0; j < 4; ++j) {
          float p = fexp2(sf[n][j]);
          sf[n][j] = p; lsum += p;
        }
    } else {
#pragma unroll
      for (int n = 0; n < 4; ++n)
#pragma unroll
        for (int j = 0; j < 4; ++j) {
          int kj = kc + n * 16 + lg * 4 + j;
          bool vld = (kj <= qi) && ((qi - kj) < W);
          float p = vld ? fexp2(sf[n][j]) : 0.f;
          sf[n][j] = p; lsum += p;
        }
    }
    // pack P (k-adjacent pairs in-register) -> per-wave LDS row q=lr
#pragma unroll
    for (int n = 0; n < 4; ++n) {
      uint2 pk;
      pk.x = cvtpk(sf[n][0], sf[n][1]);
      pk.y = cvtpk(sf[n][2], sf[n][3]);
      *(uint2*)(PlB + ((n * 32 + lg * 8) ^ swz)) = pk;
    }
    // PV: O[q][d] += P[q][k]·V[k][d]
#pragma unroll
    for (int ks = 0; ks < 2; ++ks) {
      int kgp = ks * 4 + lg;
      bf16x8 pF = *(const bf16x8*)(PlB + ((kgp * 16) ^ swz));
#pragma unroll
      for (int nd = 0; nd < 8; ++nd) {
        int d = nd * 16 + lr;
        bf16x8 vF = *(const bf16x8*)&Vs[(d << 6) + (((kgp ^ d) & 7) << 3)];
        oacc[nd] = __builtin_amdgcn_mfma_f32_16x16x32_bf16(pF, vF, oacc[nd], 0, 0, 0);
      }
    }
  }
  // total row-sum: combine the 4 lg k-slices (lanes lr, lr+16, lr+32, lr+48)
  lsum += __shfl_xor(lsum, 16);
  lsum += __shfl_xor(lsum, 32);
  const size_t obase = ((size_t)(h * 32 + qb) * 3 + c) * 8192;
  const size_t lbase = ((size_t)(h * 32 + qb) * 3 + c) * 64;
  if (l < 16) Lpart[lbase + w * 16 + lr] = lsum;
#pragma unroll
  for (int nd = 0; nd < 8; ++nd)
#pragma unroll
    for (int j = 0; j < 4; ++j) {
      int row = w * 16 + lg * 4 + j;
      int col = nd * 16 + lr;
      Opart[obase + (size_t)row * 128 + col] = oacc[nd][j];
    }
}

__global__ __launch_bounds__(256) void attn_merge(
    const float* __restrict__ Opart, const float* __restrict__ Lpart,
    u16* __restrict__ O, const int* __restrict__ wptr)
{
  const int qb = blockIdx.x, h = blockIdx.y, qb0 = qb << 6;
  const int W = read_window(wptr);
  int kstart = qb0 - W + 1;
  if (kstart < 0) kstart = 0;
  kstart &= ~63;
  const int nt = ((qb0 - kstart) >> 6) + 1;
  const size_t obase = (size_t)(h * 32 + qb) * 3 * 8192;
  const size_t lbase = (size_t)(h * 32 + qb) * 3 * 64;
  bool v0 = (0 * nt) / 3 < (1 * nt) / 3;
  bool v1 = (1 * nt) / 3 < (2 * nt) / 3;
  bool v2 = (2 * nt) / 3 < nt;
#pragma unroll
  for (int i = 0; i < 8; ++i) {
    int idx4 = threadIdx.x + (i << 8);        // 0..2047 float4 slots (64x32)
    int r = idx4 >> 5, c4 = idx4 & 31;
    float4 acc = make_float4(0.f, 0.f, 0.f, 0.f);
    float ls = 0.f;
#pragma unroll
    for (int c = 0; c < 3; ++c) {
      bool valid = c == 0 ? v0 : (c == 1 ? v1 : v2);
      if (valid) {
        float4 vv = *((const float4*)(Opart + obase + (size_t)c * 8192 + r * 128) + c4);
        acc.x += vv.x; acc.y += vv.y; acc.z += vv.z; acc.w += vv.w;
        ls += Lpart[lbase + c * 64 + r];
      }
    }
    float inv = 1.0f / ls;
    u16 o0 = f2bf(acc.x * inv), o1 = f2bf(acc.y * inv);
    u16 o2 = f2bf(acc.z * inv), o3 = f2bf(acc.w * inv);
    unsigned int lo = (unsigned int)o0 | ((unsigned int)o1 << 16);
    unsigned int hi = (unsigned int)o2 | ((unsigned int)o3 << 16);
    uint2 pk; pk.x = lo; pk.y = hi;
    *(uint2*)&O[(size_t)(qb0 + r) * DIMN + h * 128 + c4 * 4] = pk;
  }
}

// ---------------------------------------------------------------------------
extern "C" void kernel_launch(void* const* d_in, const int* in_sizes, int n_in,
                              void* d_out, int out_size, void* d_ws, size_t ws_size,
                              hipStream_t stream)
{
  (void)in_sizes; (void)n_in; (void)out_size; (void)ws_size;
  const float* x          = (const float*)d_in[0];
  const int*   ids        = (const int*)d_in[1];
  const int*   wptr       = (const int*)d_in[2];
  const float* anw        = (const float*)d_in[3];
  const float* attn_scale = (const float*)d_in[14];
  const float* q_gain     = (const float*)d_in[15];
  const float* vemb       = (const float*)d_in[16];
  const float* vpB        = (const float*)d_in[17];
  const float* mnw        = (const float*)d_in[19];
  const float* mlp_scale  = (const float*)d_in[24];

  char* ws = (char*)d_ws;
  u16* W16 = (u16*)ws;
  // packed bf16 weights: [qB;kvB], qA, kvA, [kuB;vuB], kuA, vuA, oB, oA,
  //                      vpA, fcB, fcA, fc2B, fc2A
  static const int WOFF[16] = {0, 524288, 1048576, 1572864, 1638400, 1703936,
                               1769472, 1900544, 2031616, 2555904, 3080192,
                               3096576, 3358720, 4407296, 5455872, 5718016};
  const u16* qkB16   = W16 + WOFF[0];   // 512 x 2048
  const u16* qA16    = W16 + WOFF[2];
  const u16* kvA16   = W16 + WOFF[3];
  const u16* kuvuB16 = W16 + WOFF[4];   // 512 x 256
  const u16* kuA16   = W16 + WOFF[6];
  const u16* vuA16   = W16 + WOFF[7];
  const u16* oB16    = W16 + WOFF[8];
  const u16* oA16    = W16 + WOFF[9];
  const u16* vpA16   = W16 + WOFF[10];
  const u16* fcB16   = W16 + WOFF[11];
  const u16* fcA16   = W16 + WOFF[12];
  const u16* fc2B16  = W16 + WOFF[13];
  const u16* fc2A16  = W16 + WOFF[14];

  u16*   xa16  = (u16*)(ws + 11534336);  // 8MB (norm output, q/kv then mlp)
  u16*   rb1   = (u16*)(ws + 19922944);  // 2MB rank buf (qkv ranks / o / fc)
  u16*   z16   = (u16*)(ws + 22020096);  // 1MB kv-latent; later t16 (2048x32)
  u16*   rb2   = (u16*)(ws + 23068672);  // 2MB ku/vu ranks
  u16*   k16   = (u16*)(ws + 25165824);  // 2MB
  float* v32   = (float*)(ws + 27262976);// 4MB
  u16*   vt16  = (u16*)(ws + 31457280);  // 2MB
  u16*   q16   = (u16*)(ws + 33554432);  // 8MB
  u16*   ao16  = (u16*)(ws + 41943040);  // 8MB
  float* parts = (float*)(ws + 50331648);// <=16MB split-K partials
  float* Opart = (float*)(ws + 50331648);// 50.3MB during attn (parts dead)
  float* Lpart = (float*)(ws + 19922944);// overlays rb1 during attn (dead)
  u16*   h16   = (u16*)(ws + 25165824);  // 32MB MLP hidden (k16.. dead) ->58720256
  float* parts2= (float*)(ws + 58720256);// 16MB fc2 partials (disjoint from h16)
  float* x2    = (float*)d_out;

  ConvArgs ca;
  const int widx[15] = {4, 6, 5, 7, 8, 10, 9, 11, 12, 13, 18, 20, 21, 22, 23};
  for (int i = 0; i < 15; ++i) ca.s[i] = (const float*)d_in[widx[i]];
  for (int i = 0; i < 16; ++i) ca.off[i] = WOFF[i];

  conv_weights<<<22336, 256, 0, stream>>>(ca, W16, 5718016);
  rmsnorm_k<<<2048, 256, 0, stream>>>(x, anw, xa16, 1e-6f);

  // fused hop1: xa @ [qB;kvB].T  (N=512, split-K 4)
  gemm_nt<64, 0><<<dim3(16, 4, 4), 256, 0, stream>>>(xa16, qkB16, parts, 2048, 512, 2048, 2048, nullptr, nullptr);
  redcvt_k<<<4096, 256, 0, stream>>>(parts, rb1, 1048576, 4);
  // q = rb1[:, :256] @ qA.T
  gemm_nt<64, 1><<<dim3(16, 16, 1), 256, 0, stream>>>(rb1, qA16, q16, 2048, 2048, 256, 512, nullptr, nullptr);
  // z = rb1[:, 256:] @ kvA.T
  gemm_nt<64, 1><<<dim3(16, 2, 1), 256, 0, stream>>>(rb1 + 256, kvA16, z16, 2048, 256, 256, 512, nullptr, nullptr);
  // fused ku/vu hop1: z @ [kuB;vuB].T  (N=512)
  gemm_nt<64, 1><<<dim3(16, 4, 1), 256, 0, stream>>>(z16, kuvuB16, rb2, 2048, 512, 256, 256, nullptr, nullptr);
  // k = rb2[:, :256] @ kuA.T
  gemm_nt<64, 1><<<dim3(16, 4, 1), 256, 0, stream>>>(rb2, kuA16, k16, 2048, 512, 256, 512, nullptr, nullptr);
  // v = rb2[:, 256:] @ vuA.T (f32)
  gemm_nt<64, 0><<<dim3(16, 4, 1), 256, 0, stream>>>(rb2 + 256, vuA16, v32, 2048, 512, 256, 512, nullptr, nullptr);
  // v += lr(value_emb[ids], vpB, vpA)
  g9_k<<<256, 256, 0, stream>>>(ids, vemb, vpB, z16 /* t16 reuse */);
  gemm_nt<32, 3><<<dim3(16, 4, 1), 256, 0, stream>>>(z16, vpA16, v32, 2048, 512, 32, 32, nullptr, nullptr);
  vtprep_k<<<4096, 256, 0, stream>>>(v32, vt16);
  // head norms / rope / gain*scale*log2e (q) + plain rms (k), one dispatch
  qkproc_k<<<dim3(2048, 5), 256, 0, stream>>>(q16, k16, q_gain);
  // attention: split-KV partials + merge
  attn_part<<<dim3(32, 16, 3), 256, 0, stream>>>(q16, k16, vt16, Opart, Lpart, wptr);
  attn_merge<<<dim3(32, 16), 256, 0, stream>>>(Opart, Lpart, ao16, wptr);
  // o-proj: hop1 split-8, redcvt, hop2 fused with residual (x + sc*o)
  gemm_nt<64, 0><<<dim3(16, 2, 8), 256, 0, stream>>>(ao16, oB16, parts, 2048, 256, 2048, 2048, nullptr, nullptr);
  redcvt_k<<<2048, 256, 0, stream>>>(parts, rb1, 524288, 8);
  gemm_nt<64, 4><<<dim3(16, 16, 1), 256, 0, stream>>>(rb1, oA16, x2, 2048, 2048, 256, 256, x, attn_scale);
  // mlp
  rmsnorm_k<<<2048, 256, 0, stream>>>(x2, mnw, xa16, 1e-6f);
  gemm_nt<64, 0><<<dim3(16, 1, 8), 256, 0, stream>>>(xa16, fcB16, parts, 2048, 128, 2048, 2048, nullptr, nullptr);
  redcvt_k<<<1024, 256, 0, stream>>>(parts, rb1, 262144, 8);
  gemm_nt<64, 2><<<dim3(16, 64, 1), 256, 0, stream>>>(rb1, fcA16, h16, 2048, 8192, 128, 128, nullptr, nullptr);
  gemm_nt<64, 0><<<dim3(16, 1, 16), 256, 0, stream>>>(h16, fc2B16, parts2, 2048, 128, 8192, 8192, nullptr, nullptr);
  redcvt_k<<<1024, 256, 0, stream>>>(parts2, rb1, 262144, 16);
  gemm_nt<64, 4><<<dim3(16, 16, 1), 256, 0, stream>>>(rb1, fc2A16, x2, 2048, 2048, 128, 128, x2, mlp_scale);
}

// Round 4
// 237.128 us; speedup vs baseline: 1.1976x; 1.0062x over previous
//
#include <hip/hip_runtime.h>
#include <cstdint>
#include <cstddef>

typedef unsigned short u16;
typedef __attribute__((ext_vector_type(4))) float f32x4;
typedef __attribute__((ext_vector_type(8))) short bf16x8;

#define SEQT 2048
#define DIMN 2048

__device__ __forceinline__ float bf2f(u16 h){
  union { unsigned int u; float f; } v; v.u = ((unsigned int)h) << 16; return v.f;
}
__device__ __forceinline__ u16 f2bf(float f){
  union { float f; unsigned int u; } v; v.f = f;
  unsigned int r = v.u + 0x7fffu + ((v.u >> 16) & 1u);
  return (u16)(r >> 16);
}
__device__ __forceinline__ float fexp2(float x){
  float r;
  asm("v_exp_f32 %0, %1" : "=v"(r) : "v"(x));
  return r;
}
__device__ __forceinline__ unsigned int cvtpk(float lo, float hi){
  unsigned int r;
  asm("v_cvt_pk_bf16_f32 %0, %1, %2" : "=v"(r) : "v"(lo), "v"(hi));
  return r;
}

typedef const __attribute__((address_space(1))) unsigned int* gas1_t;
typedef __attribute__((address_space(3))) unsigned int* las3_t;
__device__ __forceinline__ void gload_lds16(const void* g, void* l){
  __builtin_amdgcn_global_load_lds((gas1_t)g, (las3_t)l, 16, 0, 0);
}

// ---------------------------------------------------------------------------
// Generic NT GEMM: C[m,n] = sum_k A[m,k]*B[n,k], A:(M,lda) bf16, B:(N,K) bf16.
// BM=128, BN=128; 256 threads = 4 waves 2x2, each 64x64 (4x4 frags).
// Split-K via gridDim.z (EPI=0 only).
// EPI: 0 f32 store (+z-offset), 1 bf16 store, 2 relu^2->bf16,
//      3 f32 add-into, 4 f32 out = Xres + SC[col]*acc (residual fuse).
// ---------------------------------------------------------------------------
template<int BK, int EPI>
__global__ __launch_bounds__(256, 2) void gemm_nt(
    const u16* __restrict__ A, const u16* __restrict__ B, void* __restrict__ Cv,
    int M, int N, int K, int lda, const float* __restrict__ Xres,
    const float* __restrict__ SC)
{
  __shared__ u16 As[128 * BK];
  __shared__ u16 Bs[128 * BK];
  constexpr int ITER = (128 * BK) / 2048;
  constexpr int GM = BK / 8 - 1;
  const int t = threadIdx.x;
  const int w = t >> 6, l = t & 63;
  const int lr = l & 15, lg = l >> 4;
  const int brow = blockIdx.x << 7, bcol = blockIdx.y << 7;
  const int wr = (w >> 1) << 6, wc = (w & 1) << 6;
  const int Kc = K / gridDim.z;
  const int kbeg = blockIdx.z * Kc;
  const int kend = kbeg + Kc;
  f32x4 acc[4][4] = {};
  for (int k0 = kbeg; k0 < kend; k0 += BK) {
    __syncthreads();
#pragma unroll
    for (int i = 0; i < ITER; ++i) {
      int eo = i * 2048 + t * 8;
      int row = eo / BK;
      int cg = (eo & (BK - 1)) >> 3;
      int scol = ((cg ^ row) & GM) << 3;       // pre-swizzled global source
      gload_lds16(A + (size_t)(brow + row) * lda + k0 + scol, &As[eo]);
      gload_lds16(B + (size_t)(bcol + row) * K + k0 + scol, &Bs[eo]);
    }
    __syncthreads();
#pragma unroll
    for (int ks = 0; ks < BK / 32; ++ks) {
      bf16x8 aF[4], bF[4];
#pragma unroll
      for (int m = 0; m < 4; ++m) {
        int row = wr + m * 16 + lr;
        int kg = ks * 4 + lg;
        aF[m] = *(const bf16x8*)&As[row * BK + (((kg ^ row) & GM) << 3)];
      }
#pragma unroll
      for (int n = 0; n < 4; ++n) {
        int row = wc + n * 16 + lr;
        int kg = ks * 4 + lg;
        bF[n] = *(const bf16x8*)&Bs[row * BK + (((kg ^ row) & GM) << 3)];
      }
#pragma unroll
      for (int m = 0; m < 4; ++m)
#pragma unroll
        for (int n = 0; n < 4; ++n)
          acc[m][n] = __builtin_amdgcn_mfma_f32_16x16x32_bf16(aF[m], bF[n], acc[m][n], 0, 0, 0);
    }
  }
  const size_t zoff = (size_t)blockIdx.z * (size_t)M * (size_t)N;
#pragma unroll
  for (int m = 0; m < 4; ++m)
#pragma unroll
    for (int n = 0; n < 4; ++n)
#pragma unroll
      for (int j = 0; j < 4; ++j) {
        int row = brow + wr + m * 16 + lg * 4 + j;
        int col = bcol + wc + n * 16 + lr;
        float v = acc[m][n][j];
        if constexpr (EPI == 0) ((float*)Cv)[zoff + (size_t)row * N + col] = v;
        else if constexpr (EPI == 1) ((u16*)Cv)[(size_t)row * N + col] = f2bf(v);
        else if constexpr (EPI == 2) { float r = v > 0.f ? v * v : 0.f; ((u16*)Cv)[(size_t)row * N + col] = f2bf(r); }
        else if constexpr (EPI == 3) ((float*)Cv)[(size_t)row * N + col] += v;
        else {
          float xo = Xres[(size_t)row * N + col];
          ((float*)Cv)[(size_t)row * N + col] = xo + SC[col] * v;
        }
      }
}

// ---------------------------------------------------------------------------
// Fused MLP middle: parts[z] += relu^2(rb1 @ fcA^T)_chunk @ fc2B_chunk^T
// rb1: 2048x128 bf16, fcA: 8192x128 bf16, fc2B: 128x8192 bf16.
// Grid (16 M-blocks, 1, 16 z); each z owns 4 hidden-chunks of 128.
// GEMM1 swapped (mfma(fcA, rb1)) so hidden lands in the j-index -> cvtpk
// pairs -> swizzled LDS Hs[m][hid]; GEMM2 accumulates rank2 in regs.
// ---------------------------------------------------------------------------
__global__ __launch_bounds__(256, 1) void mlp_mid_k(
    const u16* __restrict__ rb1, const u16* __restrict__ fcA,
    const u16* __restrict__ fc2B, float* __restrict__ parts)
{
  __shared__ u16 Hs[128 * 128];
  const int t = threadIdx.x, w = t >> 6, l = t & 63;
  const int lr = l & 15, lg = l >> 4;
  const int brow = blockIdx.x << 7;
  const int z = blockIdx.z;
  const int hidOff = (w >> 1) << 6, mOff = (w & 1) << 6;   // hop1 wave layout
  const int mOff2 = (w >> 1) << 6, r2Off = (w & 1) << 6;   // hop2 wave layout
  bf16x8 rb1F[4][4];
#pragma unroll
  for (int mt = 0; mt < 4; ++mt)
#pragma unroll
    for (int ks = 0; ks < 4; ++ks)
      rb1F[mt][ks] = *(const bf16x8*)(rb1 + (size_t)(brow + mOff + mt * 16 + lr) * 128 + ks * 32 + lg * 8);
  f32x4 acc2[4][4] = {};
#pragma unroll 1
  for (int cc = 0; cc < 4; ++cc) {
    const int H0 = (z * 4 + cc) << 7;
    f32x4 acc1[4][4] = {};   // [hn][mt]
#pragma unroll
    for (int hn = 0; hn < 4; ++hn) {
      bf16x8 aF[4];
#pragma unroll
      for (int ks = 0; ks < 4; ++ks)
        aF[ks] = *(const bf16x8*)(fcA + (size_t)(H0 + hidOff + hn * 16 + lr) * 128 + ks * 32 + lg * 8);
#pragma unroll
      for (int mt = 0; mt < 4; ++mt)
#pragma unroll
        for (int ks = 0; ks < 4; ++ks)
          acc1[hn][mt] = __builtin_amdgcn_mfma_f32_16x16x32_bf16(aF[ks], rb1F[mt][ks], acc1[hn][mt], 0, 0, 0);
    }
    // relu^2 -> bf16 pack -> swizzled Hs[m][hid]
#pragma unroll
    for (int hn = 0; hn < 4; ++hn)
#pragma unroll
      for (int mt = 0; mt < 4; ++mt) {
        float r0 = acc1[hn][mt][0] > 0.f ? acc1[hn][mt][0] * acc1[hn][mt][0] : 0.f;
        float r1 = acc1[hn][mt][1] > 0.f ? acc1[hn][mt][1] * acc1[hn][mt][1] : 0.f;
        float r2 = acc1[hn][mt][2] > 0.f ? acc1[hn][mt][2] * acc1[hn][mt][2] : 0.f;
        float r3 = acc1[hn][mt][3] > 0.f ? acc1[hn][mt][3] * acc1[hn][mt][3] : 0.f;
        uint2 pk; pk.x = cvtpk(r0, r1); pk.y = cvtpk(r2, r3);
        int m = mOff + mt * 16 + lr;
        int hl = hidOff + hn * 16 + lg * 4;
        int cg = hl >> 3;
        *(uint2*)((char*)Hs + m * 256 + (((cg ^ (m & 7)) << 4) | ((hl & 7) << 1))) = pk;
      }
    __syncthreads();
#pragma unroll
    for (int ks2 = 0; ks2 < 4; ++ks2) {
      bf16x8 hF[4];
#pragma unroll
      for (int mt = 0; mt < 4; ++mt) {
        int m = mOff2 + mt * 16 + lr;
        int hl = ks2 * 32 + lg * 8;
        int cg = hl >> 3;
        hF[mt] = *(const bf16x8*)((const char*)Hs + m * 256 + (((cg ^ (m & 7)) << 4)));
      }
#pragma unroll
      for (int nf = 0; nf < 4; ++nf) {
        bf16x8 bF = *(const bf16x8*)(fc2B + (size_t)(r2Off + nf * 16 + lr) * 8192 + H0 + ks2 * 32 + lg * 8);
#pragma unroll
        for (int mt = 0; mt < 4; ++mt)
          acc2[mt][nf] = __builtin_amdgcn_mfma_f32_16x16x32_bf16(hF[mt], bF, acc2[mt][nf], 0, 0, 0);
      }
    }
    __syncthreads();
  }
  float* P = parts + (size_t)z * 2048 * 128;
#pragma unroll
  for (int mt = 0; mt < 4; ++mt)
#pragma unroll
    for (int nf = 0; nf < 4; ++nf)
#pragma unroll
      for (int j = 0; j < 4; ++j)
        P[(size_t)(brow + mOff2 + mt * 16 + lg * 4 + j) * 128 + r2Off + nf * 16 + lr] = acc2[mt][nf][j];
}

// Sum split-K partials -> bf16 (vectorized: n4 = n/4)
__global__ __launch_bounds__(256) void redcvt_k(const float* __restrict__ parts,
                                                u16* __restrict__ out, int n4, int S)
{
  int i = blockIdx.x * 256 + threadIdx.x;
  if (i >= n4) return;
  float4 s = make_float4(0.f, 0.f, 0.f, 0.f);
  for (int z = 0; z < S; ++z) {
    float4 v = ((const float4*)parts)[(size_t)z * n4 + i];
    s.x += v.x; s.y += v.y; s.z += v.z; s.w += v.w;
  }
  uint2 o; o.x = cvtpk(s.x, s.y); o.y = cvtpk(s.z, s.w);
  ((uint2*)out)[i] = o;
}

// ---------------------------------------------------------------------------
// Weight f32 -> bf16 conversion, 8 elems/thread (segment offsets all %8==0)
// ---------------------------------------------------------------------------
struct ConvArgs { const float* s[15]; int off[16]; };
__global__ __launch_bounds__(256) void conv_weights8(ConvArgs a, u16* __restrict__ dst, int total8)
{
  int i = blockIdx.x * 256 + threadIdx.x;
  if (i >= total8) return;
  int i8 = i * 8;
  int seg = 0;
#pragma unroll
  for (int k = 1; k < 15; ++k) if (i8 >= a.off[k]) seg = k;
  const float* s = a.s[seg] + (i8 - a.off[seg]);
  float4 f0 = *(const float4*)s, f1 = *(const float4*)(s + 4);
  uint4 o; o.x = cvtpk(f0.x, f0.y); o.y = cvtpk(f0.z, f0.w);
  o.z = cvtpk(f1.x, f1.y); o.w = cvtpk(f1.z, f1.w);
  *(uint4*)(dst + i8) = o;
}

// rmsnorm over DIM=2048, f32 in -> bf16 out (with weight)
__global__ __launch_bounds__(256) void rmsnorm_k(const float* __restrict__ x,
                                                 const float* __restrict__ wg,
                                                 u16* __restrict__ o, float eps)
{
  int row = blockIdx.x;
  const float* xr = x + (size_t)row * DIMN;
  float v[8]; float ss = 0.f;
#pragma unroll
  for (int i = 0; i < 8; ++i) { v[i] = xr[threadIdx.x + i * 256]; ss += v[i] * v[i]; }
#pragma unroll
  for (int m = 1; m < 64; m <<= 1) ss += __shfl_xor(ss, m);
  __shared__ float red[4];
  if ((threadIdx.x & 63) == 0) red[threadIdx.x >> 6] = ss;
  __syncthreads();
  float tot = red[0] + red[1] + red[2] + red[3];
  float rs = rsqrtf(tot * (1.0f / DIMN) + eps);
  u16* orow = o + (size_t)row * DIMN;
#pragma unroll
  for (int i = 0; i < 8; ++i) { int c = threadIdx.x + i * 256; orow[c] = f2bf(v[i] * rs * wg[c]); }
}

// per-head rms (HEPS); q path (blockIdx.y<4): RoPE + gain*scale*log2e folded;
// k path (blockIdx.y==4): plain rms. One dispatch for both.
__global__ __launch_bounds__(256) void qkproc_k(u16* __restrict__ q, u16* __restrict__ k,
                                                const float* __restrict__ gain)
{
  int tpos = blockIdx.x;
  int y = blockIdx.y;
  int wi = threadIdx.x >> 6;
  int l = threadIdx.x & 63;
  u16* p; int do_rope; float gmul;
  if (y < 4) {
    int hh = y * 4 + wi;
    p = q + (size_t)tpos * 2048 + hh * 128;
    do_rope = 1;
    gmul = gain[hh] * 0.08838834764831845f * 1.4426950408889634f; // 1/sqrt(128)*log2(e)
  } else {
    p = k + (size_t)tpos * 512 + wi * 128;
    do_rope = 0;
    gmul = 1.0f;
  }
  float v0 = bf2f(p[l]), v1 = bf2f(p[l + 64]);
  float ss = v0 * v0 + v1 * v1;
#pragma unroll
  for (int m = 1; m < 64; m <<= 1) ss += __shfl_xor(ss, m);
  float rs = rsqrtf(ss * (1.0f / 128.0f) + 1.1920929e-07f);
  v0 *= rs; v1 *= rs;
  if (do_rope) {
    int i = l & 31;
    float fr = __expf(-(float)i * 0.28782313662425574f); // ln(10000)/32
    float f = (float)tpos * fr;
    float c = cosf(f), sn = sinf(f);
    float o = __shfl_xor(v0, 32);
    v0 = (l < 32) ? (v0 * c + o * sn) : (v0 * c - o * sn);
  }
  v0 *= gmul; v1 *= gmul;
  p[l] = f2bf(v0); p[l + 64] = f2bf(v1);
}

// t16[2048][32] = value_emb[ids] @ vpB.T   (f32 inputs, bf16 out)
__global__ __launch_bounds__(256) void g9_k(const int* __restrict__ ids,
                                            const float* __restrict__ emb,
                                            const float* __restrict__ vpB,
                                            u16* __restrict__ t16)
{
  int idx = blockIdx.x * 256 + threadIdx.x;   // 2048*32
  int m = idx >> 5, n = idx & 31;
  int id = ids[m]; id = id < 0 ? 0 : (id > 50256 ? 50256 : id);
  const float* e = emb + (size_t)id * 64;
  const float* wr = vpB + n * 64;
  float s = 0.f;
#pragma unroll
  for (int k = 0; k < 64; ++k) s += e[k] * wr[k];
  t16[idx] = f2bf(s);
}

// vt[d][t] = bf16(v32[t][d]) via 64x64 LDS tile transpose
__global__ __launch_bounds__(256) void vtprep_k(const float* __restrict__ v32, u16* __restrict__ vt)
{
  __shared__ float tile[64][65];
  const int t0 = blockIdx.x << 6;    // token base (32 blocks)
  const int d0 = blockIdx.y << 6;    // d base (8 blocks)
  int tr = threadIdx.x >> 4;
  int c4 = threadIdx.x & 15;
#pragma unroll
  for (int i = 0; i < 4; ++i) {
    int row = tr + i * 16;
    float4 v = *(const float4*)(v32 + (size_t)(t0 + row) * 512 + d0 + c4 * 4);
    tile[row][c4 * 4 + 0] = v.x; tile[row][c4 * 4 + 1] = v.y;
    tile[row][c4 * 4 + 2] = v.z; tile[row][c4 * 4 + 3] = v.w;
  }
  __syncthreads();
  int dl = threadIdx.x >> 2;
  int ts = (threadIdx.x & 3) * 16;
  u16* orow = vt + (size_t)(d0 + dl) * 2048 + t0 + ts;
#pragma unroll
  for (int k = 0; k < 16; k += 2) {
    unsigned int pk = cvtpk(tile[ts + k][dl], tile[ts + k + 1][dl]);
    *(unsigned int*)(orow + k) = pk;
  }
}

// ---------------------------------------------------------------------------
// Flash attention: sliding window, SPLIT-KV, swapped QK^T, static max,
// counted-vmcnt prefetch: K double-buffered, V staged early; never drain
// vmcnt to 0 in the loop (T3/T4 minimum 2-phase).
// ---------------------------------------------------------------------------
__device__ __forceinline__ int read_window(const int* wptr){
  int W = *wptr;
  if (W > 65536 || W < 0) { union { int i; float f; } u; u.i = W; W = (int)u.f; }
  if (W < 1) W = 1;
  if (W > SEQT) W = SEQT;
  return W;
}

__global__ __launch_bounds__(256, 2) void attn_part(
    const u16* __restrict__ Q, const u16* __restrict__ Kx, const u16* __restrict__ Vt,
    float* __restrict__ Opart, float* __restrict__ Lpart, const int* __restrict__ wptr)
{
  __shared__ u16 Ks[2][64 * 128];
  __shared__ u16 Vs[128 * 64];
  __shared__ u16 Pl[4][16 * 64];
  const int t = threadIdx.x;
  const int w = t >> 6, l = t & 63;
  const int lr = l & 15, lg = l >> 4;
  const int h = blockIdx.y, kh = h >> 2;
  const int qb = blockIdx.x, qb0 = qb << 6;
  const int c = blockIdx.z;
  const int W = read_window(wptr);
  int kstart = qb0 - W + 1;
  if (kstart < 0) kstart = 0;
  kstart &= ~63;
  const int nt = ((qb0 - kstart) >> 6) + 1;
  const int tb = (c * nt) / 3, te = ((c + 1) * nt) / 3;
  if (tb >= te) return;
  bf16x8 qF[4];
  {
    const u16* qbp = Q + (size_t)(qb0 + w * 16 + lr) * DIMN + h * 128;
#pragma unroll
    for (int ks = 0; ks < 4; ++ks) qF[ks] = *(const bf16x8*)(qbp + ks * 32 + lg * 8);
  }
  f32x4 oacc[8] = {};
  float lsum = 0.f;                      // per-lane: q=lr, this lg's k-slice
  const int qi = qb0 + w * 16 + lr;
  const int swz = (lr & 7) << 4;
  char* PlB = (char*)&Pl[w][0] + lr * 128;

  auto stageK = [&](int buf, int kc){
#pragma unroll
    for (int i = 0; i < 4; ++i) {
      int eo = i * 2048 + t * 8;
      int row = eo >> 7, cg = (eo >> 3) & 15;
      gload_lds16(Kx + (size_t)(kc + row) * 512 + kh * 128 + (((cg ^ row) & 15) << 3), &Ks[buf][eo]);
    }
  };
  auto stageV = [&](int kc){
#pragma unroll
    for (int i = 0; i < 4; ++i) {
      int eo = i * 2048 + t * 8;
      int d = eo >> 6, kg = (eo >> 3) & 7;
      gload_lds16(Vt + (size_t)kh * (128 * SEQT) + (size_t)d * SEQT + kc + (((kg ^ d) & 7) << 3), &Vs[eo]);
    }
  };

  stageK(tb & 1, kstart + (tb << 6));
  for (int tt = tb; tt < te; ++tt) {
    const int kc = kstart + (tt << 6);
    stageV(kc);
    __builtin_amdgcn_sched_barrier(0);
    int tn = (tt + 1 < te) ? tt + 1 : tt;    // dummy re-stage on last iter keeps counts uniform
    stageK((tt + 1) & 1, kstart + (tn << 6));
    __builtin_amdgcn_sched_barrier(0);
    asm volatile("s_waitcnt vmcnt(8)" ::: "memory");   // K(tt) landed
    __builtin_amdgcn_s_barrier();
    // S^T = K·Q^T : sf[n][j] = S[k = kc+n*16+lg*4+j][q = qi]
    f32x4 sf[4] = {};
    const u16* KsC = &Ks[tt & 1][0];
#pragma unroll
    for (int ks = 0; ks < 4; ++ks) {
#pragma unroll
      for (int n = 0; n < 4; ++n) {
        int row = n * 16 + lr;
        int kg = ks * 4 + lg;
        bf16x8 kF = *(const bf16x8*)&KsC[(row << 7) + (((kg ^ row) & 15) << 3)];
        sf[n] = __builtin_amdgcn_mfma_f32_16x16x32_bf16(kF, qF[ks], sf[n], 0, 0, 0);
      }
    }
    const bool fullv = ((kc + 63) <= (qb0 + w * 16)) &&
                       ((qb0 + w * 16 + 15 - kc) < W);
    if (fullv) {
#pragma unroll
      for (int n = 0; n < 4; ++n)
#pragma unroll
        for (int j = 0; j < 4; ++j) {
          float p = fexp2(sf[n][j]);
          sf[n][j] = p; lsum += p;
        }
    } else {
#pragma unroll
      for (int n = 0; n < 4; ++n)
#pragma unroll
        for (int j = 0; j < 4; ++j) {
          int kj = kc + n * 16 + lg * 4 + j;
          bool vld = (kj <= qi) && ((qi - kj) < W);
          float p = vld ? fexp2(sf[n][j]) : 0.f;
          sf[n][j] = p; lsum += p;
        }
    }
    // pack P (k-adjacent pairs in-register) -> per-wave LDS row q=lr
#pragma unroll
    for (int n = 0; n < 4; ++n) {
      uint2 pk;
      pk.x = cvtpk(sf[n][0], sf[n][1]);
      pk.y = cvtpk(sf[n][2], sf[n][3]);
      *(uint2*)(PlB + ((n * 32 + lg * 8) ^ swz)) = pk;
    }
    asm volatile("s_waitcnt vmcnt(4)" ::: "memory");   // V(tt) landed (K(tt+1) still in flight)
    __builtin_amdgcn_s_barrier();
    // PV: O[q][d] += P[q][k]·V[k][d]
#pragma unroll
    for (int ks = 0; ks < 2; ++ks) {
      int kgp = ks * 4 + lg;
      bf16x8 pF = *(const bf16x8*)(PlB + ((kgp * 16) ^ swz));
#pragma unroll
      for (int nd = 0; nd < 8; ++nd) {
        int d = nd * 16 + lr;
        bf16x8 vF = *(const bf16x8*)&Vs[(d << 6) + (((kgp ^ d) & 7) << 3)];
        oacc[nd] = __builtin_amdgcn_mfma_f32_16x16x32_bf16(pF, vF, oacc[nd], 0, 0, 0);
      }
    }
    __builtin_amdgcn_s_barrier();   // PV reads done before next V-stage overwrites
  }
  // total row-sum: combine the 4 lg k-slices
  lsum += __shfl_xor(lsum, 16);
  lsum += __shfl_xor(lsum, 32);
  const size_t obase = ((size_t)(h * 32 + qb) * 3 + c) * 8192;
  const size_t lbase = ((size_t)(h * 32 + qb) * 3 + c) * 64;
  if (l < 16) Lpart[lbase + w * 16 + lr] = lsum;
#pragma unroll
  for (int nd = 0; nd < 8; ++nd)
#pragma unroll
    for (int j = 0; j < 4; ++j) {
      int row = w * 16 + lg * 4 + j;
      int col = nd * 16 + lr;
      Opart[obase + (size_t)row * 128 + col] = oacc[nd][j];
    }
}

__global__ __launch_bounds__(256) void attn_merge(
    const float* __restrict__ Opart, const float* __restrict__ Lpart,
    u16* __restrict__ O, const int* __restrict__ wptr)
{
  const int qb = blockIdx.x, h = blockIdx.y, qb0 = qb << 6;
  const int W = read_window(wptr);
  int kstart = qb0 - W + 1;
  if (kstart < 0) kstart = 0;
  kstart &= ~63;
  const int nt = ((qb0 - kstart) >> 6) + 1;
  const size_t obase = (size_t)(h * 32 + qb) * 3 * 8192;
  const size_t lbase = (size_t)(h * 32 + qb) * 3 * 64;
  bool v0 = (0 * nt) / 3 < (1 * nt) / 3;
  bool v1 = (1 * nt) / 3 < (2 * nt) / 3;
  bool v2 = (2 * nt) / 3 < nt;
#pragma unroll
  for (int i = 0; i < 8; ++i) {
    int idx4 = threadIdx.x + (i << 8);        // 0..2047 float4 slots (64x32)
    int r = idx4 >> 5, c4 = idx4 & 31;
    float4 acc = make_float4(0.f, 0.f, 0.f, 0.f);
    float ls = 0.f;
#pragma unroll
    for (int c = 0; c < 3; ++c) {
      bool valid = c == 0 ? v0 : (c == 1 ? v1 : v2);
      if (valid) {
        float4 vv = *((const float4*)(Opart + obase + (size_t)c * 8192 + r * 128) + c4);
        acc.x += vv.x; acc.y += vv.y; acc.z += vv.z; acc.w += vv.w;
        ls += Lpart[lbase + c * 64 + r];
      }
    }
    float inv = 1.0f / ls;
    uint2 pk;
    pk.x = cvtpk(acc.x * inv, acc.y * inv);
    pk.y = cvtpk(acc.z * inv, acc.w * inv);
    *(uint2*)&O[(size_t)(qb0 + r) * DIMN + h * 128 + c4 * 4] = pk;
  }
}

// ---------------------------------------------------------------------------
extern "C" void kernel_launch(void* const* d_in, const int* in_sizes, int n_in,
                              void* d_out, int out_size, void* d_ws, size_t ws_size,
                              hipStream_t stream)
{
  (void)in_sizes; (void)n_in; (void)out_size; (void)ws_size;
  const float* x          = (const float*)d_in[0];
  const int*   ids        = (const int*)d_in[1];
  const int*   wptr       = (const int*)d_in[2];
  const float* anw        = (const float*)d_in[3];
  const float* attn_scale = (const float*)d_in[14];
  const float* q_gain     = (const float*)d_in[15];
  const float* vemb       = (const float*)d_in[16];
  const float* vpB        = (const float*)d_in[17];
  const float* mnw        = (const float*)d_in[19];
  const float* mlp_scale  = (const float*)d_in[24];

  char* ws = (char*)d_ws;
  u16* W16 = (u16*)ws;
  // packed bf16 weights: [qB;kvB], qA, kvA, [kuB;vuB], kuA, vuA, oB, oA,
  //                      vpA, fcB, fcA, fc2B, fc2A
  static const int WOFF[16] = {0, 524288, 1048576, 1572864, 1638400, 1703936,
                               1769472, 1900544, 2031616, 2555904, 3080192,
                               3096576, 3358720, 4407296, 5455872, 5718016};
  const u16* qkB16   = W16 + WOFF[0];   // 512 x 2048
  const u16* qA16    = W16 + WOFF[2];
  const u16* kvA16   = W16 + WOFF[3];
  const u16* kuvuB16 = W16 + WOFF[4];   // 512 x 256
  const u16* kuA16   = W16 + WOFF[6];
  const u16* vuA16   = W16 + WOFF[7];
  const u16* oB16    = W16 + WOFF[8];
  const u16* oA16    = W16 + WOFF[9];
  const u16* vpA16   = W16 + WOFF[10];
  const u16* fcB16   = W16 + WOFF[11];
  const u16* fcA16   = W16 + WOFF[12];
  const u16* fc2B16  = W16 + WOFF[13];
  const u16* fc2A16  = W16 + WOFF[14];

  u16*   xa16  = (u16*)(ws + 11534336);  // 8MB (norm output, q/kv then mlp)
  u16*   rb1   = (u16*)(ws + 19922944);  // 2MB rank buf (qkv ranks / o / fc)
  u16*   z16   = (u16*)(ws + 22020096);  // 1MB kv-latent; later t16 (2048x32)
  u16*   rb2   = (u16*)(ws + 23068672);  // 2MB ku/vu ranks
  u16*   k16   = (u16*)(ws + 25165824);  // 2MB
  float* v32   = (float*)(ws + 27262976);// 4MB
  u16*   vt16  = (u16*)(ws + 31457280);  // 2MB
  u16*   q16   = (u16*)(ws + 33554432);  // 8MB
  u16*   ao16  = (u16*)(ws + 41943040);  // 8MB
  float* parts = (float*)(ws + 50331648);// <=16MB split-K partials
  float* Opart = (float*)(ws + 50331648);// 50.3MB during attn (parts dead)
  float* Lpart = (float*)(ws + 19922944);// overlays rb1 during attn (dead)
  float* x2    = (float*)d_out;

  ConvArgs ca;
  const int widx[15] = {4, 6, 5, 7, 8, 10, 9, 11, 12, 13, 18, 20, 21, 22, 23};
  for (int i = 0; i < 15; ++i) ca.s[i] = (const float*)d_in[widx[i]];
  for (int i = 0; i < 16; ++i) ca.off[i] = WOFF[i];

  conv_weights8<<<2792, 256, 0, stream>>>(ca, W16, 714752);
  rmsnorm_k<<<2048, 256, 0, stream>>>(x, anw, xa16, 1e-6f);

  // fused hop1: xa @ [qB;kvB].T  (N=512, split-K 4)
  gemm_nt<64, 0><<<dim3(16, 4, 4), 256, 0, stream>>>(xa16, qkB16, parts, 2048, 512, 2048, 2048, nullptr, nullptr);
  redcvt_k<<<1024, 256, 0, stream>>>(parts, rb1, 262144, 4);
  // q = rb1[:, :256] @ qA.T
  gemm_nt<64, 1><<<dim3(16, 16, 1), 256, 0, stream>>>(rb1, qA16, q16, 2048, 2048, 256, 512, nullptr, nullptr);
  // z = rb1[:, 256:] @ kvA.T
  gemm_nt<64, 1><<<dim3(16, 2, 1), 256, 0, stream>>>(rb1 + 256, kvA16, z16, 2048, 256, 256, 512, nullptr, nullptr);
  // fused ku/vu hop1: z @ [kuB;vuB].T  (N=512)
  gemm_nt<64, 1><<<dim3(16, 4, 1), 256, 0, stream>>>(z16, kuvuB16, rb2, 2048, 512, 256, 256, nullptr, nullptr);
  // k = rb2[:, :256] @ kuA.T
  gemm_nt<64, 1><<<dim3(16, 4, 1), 256, 0, stream>>>(rb2, kuA16, k16, 2048, 512, 256, 512, nullptr, nullptr);
  // v = rb2[:, 256:] @ vuA.T (f32)
  gemm_nt<64, 0><<<dim3(16, 4, 1), 256, 0, stream>>>(rb2 + 256, vuA16, v32, 2048, 512, 256, 512, nullptr, nullptr);
  // v += lr(value_emb[ids], vpB, vpA)
  g9_k<<<256, 256, 0, stream>>>(ids, vemb, vpB, z16 /* t16 reuse */);
  gemm_nt<32, 3><<<dim3(16, 4, 1), 256, 0, stream>>>(z16, vpA16, v32, 2048, 512, 32, 32, nullptr, nullptr);
  vtprep_k<<<dim3(32, 8), 256, 0, stream>>>(v32, vt16);
  // head norms / rope / gain*scale*log2e (q) + plain rms (k), one dispatch
  qkproc_k<<<dim3(2048, 5), 256, 0, stream>>>(q16, k16, q_gain);
  // attention: split-KV partials + merge
  attn_part<<<dim3(32, 16, 3), 256, 0, stream>>>(q16, k16, vt16, Opart, Lpart, wptr);
  attn_merge<<<dim3(32, 16), 256, 0, stream>>>(Opart, Lpart, ao16, wptr);
  // o-proj: hop1 split-8, redcvt, hop2 fused with residual (x + sc*o)
  gemm_nt<64, 0><<<dim3(16, 2, 8), 256, 0, stream>>>(ao16, oB16, parts, 2048, 256, 2048, 2048, nullptr, nullptr);
  redcvt_k<<<512, 256, 0, stream>>>(parts, rb1, 131072, 8);
  gemm_nt<64, 4><<<dim3(16, 16, 1), 256, 0, stream>>>(rb1, oA16, x2, 2048, 2048, 256, 256, x, attn_scale);
  // mlp
  rmsnorm_k<<<2048, 256, 0, stream>>>(x2, mnw, xa16, 1e-6f);
  gemm_nt<64, 0><<<dim3(16, 1, 8), 256, 0, stream>>>(xa16, fcB16, parts, 2048, 128, 2048, 2048, nullptr, nullptr);
  redcvt_k<<<256, 256, 0, stream>>>(parts, rb1, 65536, 8);
  // fused MLP middle: relu^2(rb1@fcA.T)@fc2B.T -> parts (16 z-slices)
  mlp_mid_k<<<dim3(16, 1, 16), 256, 0, stream>>>(rb1, fcA16, fc2B16, parts);
  redcvt_k<<<256, 256, 0, stream>>>(parts, rb1, 65536, 16);
  gemm_nt<64, 4><<<dim3(16, 16, 1), 256, 0, stream>>>(rb1, fc2A16, x2, 2048, 2048, 128, 128, x2, mlp_scale);
}